// Round 8
// baseline (165.228 us; speedup 1.0000x reference)
//
#include <hip/hip_runtime.h>
#include <stdint.h>

typedef __bf16 bf16;
typedef bf16 bf16x8 __attribute__((ext_vector_type(8)));
typedef bf16 bf16x4 __attribute__((ext_vector_type(4)));
typedef float f32x4 __attribute__((ext_vector_type(4)));

#define B_   2
#define S_   1024
#define D_   2048
#define H_   16
#define DH_  128
#define M_   (B_*S_)
#define EPSF 1e-6f

__device__ __forceinline__ void gload_lds16(const void* g, void* l) {
    __builtin_amdgcn_global_load_lds(
        (const __attribute__((address_space(1))) void*)g,
        (__attribute__((address_space(3))) void*)l,
        16, 0, 0);
}

// ---------------- fused conversion kernel (x, wq, wk, wv; wo is done inside gemm8p z=3) ----------------
struct ConvArgs {
    const void* s[4];
    bf16* d[4];
};

__global__ __launch_bounds__(256) void conv_all(ConvArgs a, int n) {
    const int z = blockIdx.y;
    const int i = (blockIdx.x * 256 + threadIdx.x) * 8;
    if (i + 8 > n) return;
    bf16x8 o;
    if (z == 0) {
        const float* src = (const float*)a.s[0];
        float4 v0 = *(const float4*)(src + i);
        float4 v1 = *(const float4*)(src + i + 4);
        o[0] = (bf16)v0.x; o[1] = (bf16)v0.y; o[2] = (bf16)v0.z; o[3] = (bf16)v0.w;
        o[4] = (bf16)v1.x; o[5] = (bf16)v1.y; o[6] = (bf16)v1.z; o[7] = (bf16)v1.w;
    } else {
        const int* src = (const int*)a.s[z];
        int4 v0 = *(const int4*)(src + i);
        int4 v1 = *(const int4*)(src + i + 4);
        o[0] = (bf16)(float)v0.x; o[1] = (bf16)(float)v0.y;
        o[2] = (bf16)(float)v0.z; o[3] = (bf16)(float)v0.w;
        o[4] = (bf16)(float)v1.x; o[5] = (bf16)(float)v1.y;
        o[6] = (bf16)(float)v1.z; o[7] = (bf16)(float)v1.w;
    }
    *(bf16x8*)(a.d[z] + i) = o;
}

// ---------------- 8-phase 256x256 GEMM (QKV) + wo-conv side z-slice ----------------
struct GemmArgs {
    const bf16* W[3];
    const float* Sc[3];
    void* O[3];
    int mode[3];
    const int* wo_src;
    bf16* wo_dst;
};

__global__ __launch_bounds__(512, 2) void gemm8p(const bf16* __restrict__ A, GemmArgs args) {
    __shared__ char lds[131072];
    constexpr int NT = D_ / 64;   // 32 K-tiles
    const int z = blockIdx.z;
    const int t = threadIdx.x;

    if (z == 3) {
        const int flat = blockIdx.y * 8 + blockIdx.x;
        const int* src = args.wo_src + (size_t)flat * 65536;
        bf16* dst = args.wo_dst + (size_t)flat * 65536;
#pragma unroll
        for (int it = 0; it < 16; ++it) {
            int off = it * 4096 + t * 8;
            int4 v0 = *(const int4*)(src + off);
            int4 v1 = *(const int4*)(src + off + 4);
            bf16x8 o;
            o[0] = (bf16)(float)v0.x; o[1] = (bf16)(float)v0.y;
            o[2] = (bf16)(float)v0.z; o[3] = (bf16)(float)v0.w;
            o[4] = (bf16)(float)v1.x; o[5] = (bf16)(float)v1.y;
            o[6] = (bf16)(float)v1.z; o[7] = (bf16)(float)v1.w;
            *(bf16x8*)(dst + off) = o;
        }
        return;
    }

    const bf16* __restrict__ Wz = args.W[z];
    const float* __restrict__ Sc = args.Sc[z];
    const int mode = args.mode[z];
    const int w = t >> 6, l = t & 63;
    const int wr = w >> 2, wc = w & 3;
    const int m0 = blockIdx.y * 256, n0 = blockIdx.x * 256;
    const int hi = l >> 4, lo = l & 15;

    const int r8 = l >> 3;
    const int ce = ((l & 7) ^ (r8 & 7)) * 8;   // pre-swizzled source column
    const bf16* Ag = A  + (size_t)(m0 + w * 8 + r8) * D_ + ce;
    const bf16* Bg = Wz + (size_t)(n0 + w * 8 + r8) * D_ + ce;

    auto stage = [&](int kt, int q) {
        if (kt >= NT) return;
        const bf16* g = (q < 2 ? Ag : Bg) + (size_t)((q & 1) * 128) * D_ + (size_t)kt * 64;
        char* d = lds + ((kt & 1) ? 65536 : 0) + q * 16384 + w * 1024;
        gload_lds16((const void*)g, (void*)d);
        gload_lds16((const void*)(g + (size_t)64 * D_), (void*)(d + 8192));
    };

    f32x4 acc[8][4] = {};

    stage(0, 0); stage(0, 1); stage(0, 2); stage(0, 3);
    stage(1, 2); stage(1, 0);
    asm volatile("s_waitcnt vmcnt(4)" ::: "memory");
    asm volatile("s_barrier" ::: "memory");

    for (int kt = 0; kt < NT; ++kt) {
        const char* Pb = lds + ((kt & 1) ? 65536 : 0);
        const char* As = Pb;
        const char* Bs = Pb + 32768;
        bf16x8 a[4][2], b01[2][2], b23[2][2];

        auto rdA = [&](int mi, int kk) -> bf16x8 {
            int row = wr * 128 + mi * 16 + lo;
            return *(const bf16x8*)(As + row * 128 + ((kk * 64 + hi * 16) ^ ((row & 7) << 4)));
        };
        auto rdB = [&](int ni, int kk) -> bf16x8 {
            int row = wc * 64 + ni * 16 + lo;
            return *(const bf16x8*)(Bs + row * 128 + ((kk * 64 + hi * 16) ^ ((row & 7) << 4)));
        };

        // ---- p0: A0-3 x B0-1 ----
#pragma unroll
        for (int mi = 0; mi < 4; ++mi) { a[mi][0] = rdA(mi, 0); a[mi][1] = rdA(mi, 1); }
#pragma unroll
        for (int ni = 0; ni < 2; ++ni) { b01[ni][0] = rdB(ni, 0); b01[ni][1] = rdB(ni, 1); }
        stage(kt + 1, 1);
        asm volatile("s_barrier" ::: "memory");
        asm volatile("s_waitcnt lgkmcnt(0)" ::: "memory");
        __builtin_amdgcn_sched_barrier(0);
        __builtin_amdgcn_s_setprio(1);
#pragma unroll
        for (int mi = 0; mi < 4; ++mi)
#pragma unroll
            for (int ni = 0; ni < 2; ++ni)
#pragma unroll
                for (int kk = 0; kk < 2; ++kk)
                    acc[mi][ni] = __builtin_amdgcn_mfma_f32_16x16x32_bf16(a[mi][kk], b01[ni][kk], acc[mi][ni], 0, 0, 0);
        __builtin_amdgcn_s_setprio(0);
        asm volatile("s_barrier" ::: "memory");

        // ---- p1: A0-3 x B2-3 ----
#pragma unroll
        for (int ni = 0; ni < 2; ++ni) { b23[ni][0] = rdB(2 + ni, 0); b23[ni][1] = rdB(2 + ni, 1); }
        stage(kt + 1, 3);
        asm volatile("s_barrier" ::: "memory");
        asm volatile("s_waitcnt lgkmcnt(0)" ::: "memory");
        __builtin_amdgcn_sched_barrier(0);
        __builtin_amdgcn_s_setprio(1);
#pragma unroll
        for (int mi = 0; mi < 4; ++mi)
#pragma unroll
            for (int ni = 0; ni < 2; ++ni)
#pragma unroll
                for (int kk = 0; kk < 2; ++kk)
                    acc[mi][2 + ni] = __builtin_amdgcn_mfma_f32_16x16x32_bf16(a[mi][kk], b23[ni][kk], acc[mi][2 + ni], 0, 0, 0);
        __builtin_amdgcn_s_setprio(0);
        asm volatile("s_barrier" ::: "memory");

        // ---- p2: A4-7 x B2-3 ----
#pragma unroll
        for (int mi = 0; mi < 4; ++mi) { a[mi][0] = rdA(4 + mi, 0); a[mi][1] = rdA(4 + mi, 1); }
        stage(kt + 2, 2);
        asm volatile("s_barrier" ::: "memory");
        asm volatile("s_waitcnt lgkmcnt(0)" ::: "memory");
        __builtin_amdgcn_sched_barrier(0);
        __builtin_amdgcn_s_setprio(1);
#pragma unroll
        for (int mi = 0; mi < 4; ++mi)
#pragma unroll
            for (int ni = 0; ni < 2; ++ni)
#pragma unroll
                for (int kk = 0; kk < 2; ++kk)
                    acc[4 + mi][2 + ni] = __builtin_amdgcn_mfma_f32_16x16x32_bf16(a[mi][kk], b23[ni][kk], acc[4 + mi][2 + ni], 0, 0, 0);
        __builtin_amdgcn_s_setprio(0);
        asm volatile("s_barrier" ::: "memory");

        // ---- p3: A4-7 x B0-1 ----
        stage(kt + 2, 0);
        asm volatile("s_barrier" ::: "memory");
        __builtin_amdgcn_sched_barrier(0);
        __builtin_amdgcn_s_setprio(1);
#pragma unroll
        for (int mi = 0; mi < 4; ++mi)
#pragma unroll
            for (int ni = 0; ni < 2; ++ni)
#pragma unroll
                for (int kk = 0; kk < 2; ++kk)
                    acc[4 + mi][ni] = __builtin_amdgcn_mfma_f32_16x16x32_bf16(a[mi][kk], b01[ni][kk], acc[4 + mi][ni], 0, 0, 0);
        __builtin_amdgcn_s_setprio(0);
        if (kt < NT - 2) asm volatile("s_waitcnt vmcnt(4)" ::: "memory");
        else             asm volatile("s_waitcnt vmcnt(0)" ::: "memory");
        asm volatile("s_barrier" ::: "memory");
    }

#pragma unroll
    for (int ni = 0; ni < 4; ++ni) {
        const int n = n0 + wc * 64 + ni * 16 + lo;
        const float scv = Sc[n];
#pragma unroll
        for (int mi = 0; mi < 8; ++mi) {
            const int mb = m0 + wr * 128 + mi * 16 + hi * 4;
            if (mode == 1) {
                bf16x4 pk;
#pragma unroll
                for (int r = 0; r < 4; ++r) pk[r] = (bf16)(acc[mi][ni][r] * scv);
                const int bb = mb >> 10, s = mb & 1023, hh = n >> 7, dh = n & 127;
                *(bf16x4*)(((bf16*)args.O[z]) + (((size_t)(bb * H_ + hh)) * DH_ + dh) * S_ + s) = pk;
            } else {
#pragma unroll
                for (int r = 0; r < 4; ++r)
                    ((bf16*)args.O[z])[(size_t)(mb + r) * D_ + n] = (bf16)(acc[mi][ni][r] * scv);
            }
        }
    }
}

// ---------------- O-proj GEMM: BM=BN=128, 4 waves, 2-phase counted vmcnt ----------------
__global__ __launch_bounds__(256, 2) void gemmO(const bf16* __restrict__ A, const bf16* __restrict__ W,
                                                const float* __restrict__ Sc, float* __restrict__ O) {
    __shared__ char lds[65536];
    constexpr int NT = D_ / 64;
    const int t = threadIdx.x;
    const int w = t >> 6, l = t & 63;
    const int wr = w >> 1, wc = w & 1;
    const int m0 = blockIdx.y * 128, n0 = blockIdx.x * 128;
    const int hi = l >> 4, lo = l & 15;

    const int r8 = l >> 3;
    const int ce = ((l & 7) ^ (r8 & 7)) * 8;
    const bf16* Ag = A + (size_t)(m0 + w * 8 + r8) * D_ + ce;
    const bf16* Bg = W + (size_t)(n0 + w * 8 + r8) * D_ + ce;

    auto stage = [&](int kt) {
        char* d = lds + (kt & 1) * 32768 + w * 1024;
        const bf16* ga = Ag + (size_t)kt * 64;
        const bf16* gb = Bg + (size_t)kt * 64;
#pragma unroll
        for (int j = 0; j < 4; ++j) {
            gload_lds16((const void*)(ga + (size_t)j * 32 * D_), (void*)(d + j * 4096));
            gload_lds16((const void*)(gb + (size_t)j * 32 * D_), (void*)(d + 16384 + j * 4096));
        }
    };

    f32x4 acc[4][4] = {};
    stage(0);
    for (int kt = 0; kt < NT; ++kt) {
        const char* cur = lds + (kt & 1) * 32768;
        if (kt + 1 < NT) {
            stage(kt + 1);
            asm volatile("s_waitcnt vmcnt(8)" ::: "memory");
        } else {
            asm volatile("s_waitcnt vmcnt(0)" ::: "memory");
        }
        asm volatile("s_barrier" ::: "memory");

        bf16x8 a[4][2], b[4][2];
#pragma unroll
        for (int mi = 0; mi < 4; ++mi)
#pragma unroll
            for (int kk = 0; kk < 2; ++kk) {
                int row = wr * 64 + mi * 16 + lo;
                a[mi][kk] = *(const bf16x8*)(cur + row * 128 + ((kk * 64 + hi * 16) ^ ((row & 7) << 4)));
            }
#pragma unroll
        for (int ni = 0; ni < 4; ++ni)
#pragma unroll
            for (int kk = 0; kk < 2; ++kk) {
                int row = wc * 64 + ni * 16 + lo;
                b[ni][kk] = *(const bf16x8*)(cur + 16384 + row * 128 + ((kk * 64 + hi * 16) ^ ((row & 7) << 4)));
            }
        __builtin_amdgcn_s_setprio(1);
#pragma unroll
        for (int mi = 0; mi < 4; ++mi)
#pragma unroll
            for (int ni = 0; ni < 4; ++ni)
#pragma unroll
                for (int kk = 0; kk < 2; ++kk)
                    acc[mi][ni] = __builtin_amdgcn_mfma_f32_16x16x32_bf16(a[mi][kk], b[ni][kk], acc[mi][ni], 0, 0, 0);
        __builtin_amdgcn_s_setprio(0);
        asm volatile("s_barrier" ::: "memory");
    }

#pragma unroll
    for (int ni = 0; ni < 4; ++ni) {
        const int n = n0 + wc * 64 + ni * 16 + lo;
        const float scv = Sc[n];
#pragma unroll
        for (int mi = 0; mi < 4; ++mi) {
            const int mb = m0 + wr * 64 + mi * 16 + hi * 4;
#pragma unroll
            for (int r = 0; r < 4; ++r)
                O[(size_t)(mb + r) * D_ + n] = acc[mi][ni][r] * scv;
        }
    }
}

// ---------------- RMSNorm + RoPE + transpose to [B,H,S,Dh] ----------------
__global__ __launch_bounds__(256) void rope_norm(const bf16* __restrict__ qr, const bf16* __restrict__ kr,
                                                 const float* __restrict__ qn, const float* __restrict__ kn,
                                                 const float* __restrict__ cosT, const float* __restrict__ sinT,
                                                 bf16* __restrict__ qOut, bf16* __restrict__ kOut) {
    const int which = blockIdx.z;
    const bf16* src = which ? kr : qr;
    const float* nw = which ? kn : qn;
    bf16* dst = which ? kOut : qOut;
    const int row = blockIdx.x;           // b*S + s
    const int b = row >> 10, s = row & 1023;
    const int t = threadIdx.x;
    __shared__ float xs[D_];
    __shared__ float red[4];

    bf16x8 v = *(const bf16x8*)(src + (size_t)row * D_ + t * 8);
    float x[8]; float ss = 0.f;
#pragma unroll
    for (int j = 0; j < 8; ++j) { x[j] = (float)v[j]; ss += x[j] * x[j]; xs[t * 8 + j] = x[j]; }
#pragma unroll
    for (int msk = 32; msk; msk >>= 1) ss += __shfl_xor(ss, msk, 64);
    if ((t & 63) == 0) red[t >> 6] = ss;
    __syncthreads();
    const float inv = rsqrtf((red[0] + red[1] + red[2] + red[3]) / (float)D_ + EPSF);

    const int h = t >> 4;
    const int dh0 = (t & 15) * 8;
    bf16x8 o;
#pragma unroll
    for (int j = 0; j < 8; ++j) {
        int dd = dh0 + j;
        int d = h * 128 + dd;
        int pd = (dd < 64) ? d + 64 : d - 64;
        float xn = x[j] * inv * nw[d];
        float xp = xs[pd] * inv * nw[pd];
        float rot = (dd < 64) ? -xp : xp;
        o[j] = (bf16)(xn * cosT[s * DH_ + dd] + rot * sinT[s * DH_ + dd]);
    }
    *(bf16x8*)(dst + (((size_t)(b * H_ + h)) * S_ + s) * DH_ + dh0) = o;
}

// ---------------- flash attention: Q64, K double-buffered, counted-vmcnt pipeline, defer-max ----------------
// Q,K: [B,H,S,Dh] ; VT: [B,H,Dh,S] ; Out: [B*S, D] bf16
__global__ __launch_bounds__(256) void flash(const bf16* __restrict__ Q, const bf16* __restrict__ Kb,
                                             const bf16* __restrict__ VTb, const int* __restrict__ lengths,
                                             bf16* __restrict__ Out) {
    __shared__ bf16 Qs[64 * 128];
    __shared__ bf16 Kdb[2][64 * 128];
    __shared__ bf16 Vt[128 * 64];
    __shared__ bf16 Ps[4][16 * 64];
    const int t = threadIdx.x, w = t >> 6, l = t & 63;
    const int bh = blockIdx.y;
    const int b = bh >> 4;
    const int q0 = blockIdx.x * 64;
    const int L = lengths[b];
    const size_t base = (size_t)bh * S_ * DH_;
    const size_t vbase = (size_t)bh * DH_ * S_;
    const int hi = l >> 4, lo = l & 15;
    const int swz = (lo & 7) << 3;
    const int nt = (L + 63) >> 6;
    const float sscale = 0.08838834764831843f;

    // row/col for K/Q staging (pre-swizzled source)
    const int srow = (l >> 4);               // 0..3 within 4-row group
    const int sb_qk = ((l & 15) * 16);       // byte col
    // V staging
    const int svrow = (l >> 3);
    const int sb_v = ((l & 7) * 16);

    // prologue: Q (4), then K0 (4), then V0 (4) -> vmcnt(4) retires Q+K0
    {
        const bf16* qsrc = Q + base + (size_t)q0 * DH_;
#pragma unroll
        for (int i = 0; i < 4; ++i) {
            int r = (w * 4 + i) * 4 + srow;
            int sb = sb_qk ^ ((r & 7) << 4);
            gload_lds16((const void*)((const char*)(qsrc + (size_t)r * DH_) + sb), (void*)(Qs + (w * 4 + i) * 512));
        }
        const bf16* ksrc = Kb + base;
#pragma unroll
        for (int i = 0; i < 4; ++i) {
            int r = (w * 4 + i) * 4 + srow;
            int sb = sb_qk ^ ((r & 7) << 4);
            gload_lds16((const void*)((const char*)(ksrc + (size_t)r * DH_) + sb), (void*)(Kdb[0] + (w * 4 + i) * 512));
        }
        const bf16* vsrc = VTb + vbase;
#pragma unroll
        for (int i = 0; i < 4; ++i) {
            int d = (w * 4 + i) * 8 + svrow;
            int sb = sb_v ^ ((d & 7) << 4);
            gload_lds16((const void*)((const char*)(vsrc + (size_t)d * S_) + sb), (void*)(Vt + (w * 4 + i) * 512));
        }
    }

    f32x4 O[8] = {};
    float mrow[4], lrow[4];
#pragma unroll
    for (int r = 0; r < 4; ++r) { mrow[r] = -1e30f; lrow[r] = 0.f; }

    for (int kt = 0; kt < nt; ++kt) {
        const int k0 = kt * 64;
        const bool pre = (kt + 1 < nt);

        // top: K(kt)+Q retired (V(kt) = 4 newest still in flight)
        asm volatile("s_waitcnt vmcnt(4)" ::: "memory");
        asm volatile("s_barrier" ::: "memory");

        const bf16* Ks = Kdb[kt & 1];
        // QK^T
        f32x4 sc[4] = {};
        __builtin_amdgcn_s_setprio(1);
#pragma unroll
        for (int kk = 0; kk < 4; ++kk) {
            const int ko = kk * 32 + hi * 8;
            bf16x8 aq = *(const bf16x8*)(Qs + (w * 16 + lo) * 128 + (ko ^ swz));
#pragma unroll
            for (int ni = 0; ni < 4; ++ni) {
                bf16x8 bk = *(const bf16x8*)(Ks + (ni * 16 + lo) * 128 + (ko ^ swz));
                sc[ni] = __builtin_amdgcn_mfma_f32_16x16x32_bf16(aq, bk, sc[ni], 0, 0, 0);
            }
        }
        __builtin_amdgcn_s_setprio(0);

        // issue next-K stage into the other K buffer (overlaps softmax+PV)
        if (pre) {
            const bf16* ksrc = Kb + base + (size_t)(k0 + 64) * DH_;
            bf16* kdst = Kdb[(kt + 1) & 1];
#pragma unroll
            for (int i = 0; i < 4; ++i) {
                int r = (w * 4 + i) * 4 + srow;
                int sb = sb_qk ^ ((r & 7) << 4);
                gload_lds16((const void*)((const char*)(ksrc + (size_t)r * DH_) + sb), (void*)(kdst + (w * 4 + i) * 512));
            }
        }

        // online softmax (defer-max, THR=8)
        float p[4][4];
#pragma unroll
        for (int r = 0; r < 4; ++r) {
            float sv[4]; float vmax = -1e30f;
#pragma unroll
            for (int ni = 0; ni < 4; ++ni) {
                int kg = k0 + ni * 16 + lo;
                float vv = sc[ni][r] * sscale;
                if (kg >= L) vv = -1e30f;
                sv[ni] = vv;
                vmax = fmaxf(vmax, vv);
            }
#pragma unroll
            for (int msk = 1; msk < 16; msk <<= 1) vmax = fmaxf(vmax, __shfl_xor(vmax, msk, 64));
            float mnew, corr;
            if (vmax <= mrow[r] + 8.f) { mnew = mrow[r]; corr = 1.f; }
            else { mnew = vmax; corr = __expf(mrow[r] - mnew); }
            float rs = 0.f;
#pragma unroll
            for (int ni = 0; ni < 4; ++ni) { float pv = __expf(sv[ni] - mnew); p[r][ni] = pv; rs += pv; }
#pragma unroll
            for (int msk = 1; msk < 16; msk <<= 1) rs += __shfl_xor(rs, msk, 64);
            lrow[r] = lrow[r] * corr + rs;
            mrow[r] = mnew;
            if (corr != 1.f) {
#pragma unroll
                for (int di = 0; di < 8; ++di) O[di][r] *= corr;
            }
        }

        // V(kt) ready: outstanding = V(kt) older + K(kt+1) newer
        if (pre) asm volatile("s_waitcnt vmcnt(4)" ::: "memory");
        else     asm volatile("s_waitcnt vmcnt(0)" ::: "memory");
        asm volatile("s_barrier" ::: "memory");

        // P -> LDS (per-wave buffer), swizzled
#pragma unroll
        for (int r = 0; r < 4; ++r) {
            int prow = hi * 4 + r;
#pragma unroll
            for (int ni = 0; ni < 4; ++ni)
                Ps[w][prow * 64 + (((ni * 16 + lo)) ^ ((prow & 7) << 3))] = (bf16)p[r][ni];
        }

        // PV
        __builtin_amdgcn_s_setprio(1);
#pragma unroll
        for (int kk = 0; kk < 2; ++kk) {
            const int ko = kk * 32 + hi * 8;
            bf16x8 ap = *(const bf16x8*)(&Ps[w][lo * 64 + (ko ^ swz)]);
#pragma unroll
            for (int di = 0; di < 8; ++di) {
                bf16x8 bv = *(const bf16x8*)(Vt + (di * 16 + lo) * 64 + (ko ^ swz));
                O[di] = __builtin_amdgcn_mfma_f32_16x16x32_bf16(ap, bv, O[di], 0, 0, 0);
            }
        }
        __builtin_amdgcn_s_setprio(0);

        // all PV reads of Vt done -> stage next V late (overlaps next QK^T+softmax)
        asm volatile("s_barrier" ::: "memory");
        if (pre) {
            const bf16* vsrc = VTb + vbase + (k0 + 64);
#pragma unroll
            for (int i = 0; i < 4; ++i) {
                int d = (w * 4 + i) * 8 + svrow;
                int sb = sb_v ^ ((d & 7) << 4);
                gload_lds16((const void*)((const char*)(vsrc + (size_t)d * S_) + sb), (void*)(Vt + (w * 4 + i) * 512));
            }
        }
    }

    const int h = bh & 15;
#pragma unroll
    for (int r = 0; r < 4; ++r) {
        float invl = 1.0f / lrow[r];
        int qrow = q0 + w * 16 + hi * 4 + r;
        bf16* orow = Out + (size_t)(b * S_ + qrow) * D_ + h * DH_;
#pragma unroll
        for (int di = 0; di < 8; ++di)
            orow[di * 16 + lo] = (bf16)(O[di][r] * invl);
    }
}

// ---------------- launch ----------------
extern "C" void kernel_launch(void* const* d_in, const int* in_sizes, int n_in,
                              void* d_out, int out_size, void* d_ws, size_t ws_size,
                              hipStream_t stream) {
    const float* x    = (const float*)d_in[0];
    const float* wq_s = (const float*)d_in[1];
    const float* wk_s = (const float*)d_in[2];
    const float* wv_s = (const float*)d_in[3];
    const float* wo_s = (const float*)d_in[4];
    const float* qn   = (const float*)d_in[5];
    const float* kn   = (const float*)d_in[6];
    const float* cosT = (const float*)d_in[7];
    const float* sinT = (const float*)d_in[8];
    const int* wq = (const int*)d_in[9];
    const int* wk = (const int*)d_in[10];
    const int* wv = (const int*)d_in[11];
    const int* wo = (const int*)d_in[12];
    const int* lengths = (const int*)d_in[13];
    float* out = (float*)d_out;

    char* ws = (char*)d_ws;
    const size_t SLOT = (size_t)M_ * D_ * sizeof(bf16);  // 8 MiB
    bf16* xb   = (bf16*)(ws);
    bf16* wqb  = (bf16*)(ws + 1 * SLOT);
    bf16* wkb  = (bf16*)(ws + 2 * SLOT);
    bf16* wvb  = (bf16*)(ws + 3 * SLOT);
    bf16* wob  = (bf16*)(ws + 4 * SLOT);
    bf16* qr   = (bf16*)(ws + 5 * SLOT);
    bf16* kr   = (bf16*)(ws + 6 * SLOT);
    bf16* qb2  = (bf16*)(ws + 7 * SLOT);
    bf16* kb2  = (bf16*)(ws + 8 * SLOT);
    bf16* vb2  = (bf16*)(ws + 9 * SLOT);  // V^T layout [B,H,Dh,S]
    bf16* attnb = qr;   // reuse after rope_norm

    const int NW = D_ * D_;  // 4194304
    ConvArgs ca;
    ca.s[0] = x;  ca.d[0] = xb;
    ca.s[1] = wq; ca.d[1] = wqb;
    ca.s[2] = wk; ca.d[2] = wkb;
    ca.s[3] = wv; ca.d[3] = wvb;
    conv_all<<<dim3(NW / 2048, 4), dim3(256), 0, stream>>>(ca, NW);

    GemmArgs ga;
    ga.W[0] = wqb; ga.W[1] = wkb; ga.W[2] = wvb;
    ga.Sc[0] = wq_s; ga.Sc[1] = wk_s; ga.Sc[2] = wv_s;
    ga.O[0] = qr; ga.O[1] = kr; ga.O[2] = vb2;
    ga.mode[0] = 2; ga.mode[1] = 2; ga.mode[2] = 1;
    ga.wo_src = wo; ga.wo_dst = wob;
    gemm8p<<<dim3(D_ / 256, M_ / 256, 4), dim3(512), 0, stream>>>(xb, ga);

    rope_norm<<<dim3(M_, 1, 2), dim3(256), 0, stream>>>(qr, kr, qn, kn, cosT, sinT, qb2, kb2);

    flash<<<dim3(S_ / 64, B_ * H_, 1), dim3(256), 0, stream>>>(qb2, kb2, vb2, lengths, attnb);

    gemmO<<<dim3(D_ / 128, M_ / 128), dim3(256), 0, stream>>>(attnb, wob, wo_s, out);
}

// Round 9
// 162.533 us; speedup vs baseline: 1.0166x; 1.0166x over previous
//
#include <hip/hip_runtime.h>
#include <stdint.h>

typedef __bf16 bf16;
typedef bf16 bf16x8 __attribute__((ext_vector_type(8)));
typedef bf16 bf16x4 __attribute__((ext_vector_type(4)));
typedef float f32x4 __attribute__((ext_vector_type(4)));

#define B_   2
#define S_   1024
#define D_   2048
#define H_   16
#define DH_  128
#define M_   (B_*S_)
#define EPSF 1e-6f

__device__ __forceinline__ void gload_lds16(const void* g, void* l) {
    __builtin_amdgcn_global_load_lds(
        (const __attribute__((address_space(1))) void*)g,
        (__attribute__((address_space(3))) void*)l,
        16, 0, 0);
}

// ---------------- fused conversion kernel (x, wq, wk, wv; wo is done inside gemm8p z=3) ----------------
struct ConvArgs {
    const void* s[4];
    bf16* d[4];
};

__global__ __launch_bounds__(256) void conv_all(ConvArgs a, int n) {
    const int z = blockIdx.y;
    const int i = (blockIdx.x * 256 + threadIdx.x) * 8;
    if (i + 8 > n) return;
    bf16x8 o;
    if (z == 0) {
        const float* src = (const float*)a.s[0];
        float4 v0 = *(const float4*)(src + i);
        float4 v1 = *(const float4*)(src + i + 4);
        o[0] = (bf16)v0.x; o[1] = (bf16)v0.y; o[2] = (bf16)v0.z; o[3] = (bf16)v0.w;
        o[4] = (bf16)v1.x; o[5] = (bf16)v1.y; o[6] = (bf16)v1.z; o[7] = (bf16)v1.w;
    } else {
        const int* src = (const int*)a.s[z];
        int4 v0 = *(const int4*)(src + i);
        int4 v1 = *(const int4*)(src + i + 4);
        o[0] = (bf16)(float)v0.x; o[1] = (bf16)(float)v0.y;
        o[2] = (bf16)(float)v0.z; o[3] = (bf16)(float)v0.w;
        o[4] = (bf16)(float)v1.x; o[5] = (bf16)(float)v1.y;
        o[6] = (bf16)(float)v1.z; o[7] = (bf16)(float)v1.w;
    }
    *(bf16x8*)(a.d[z] + i) = o;
}

// ---------------- 8-phase 256x256 GEMM (QKV) + wo-conv side z-slice ----------------
struct GemmArgs {
    const bf16* W[3];
    const float* Sc[3];
    void* O[3];
    int mode[3];
    const int* wo_src;
    bf16* wo_dst;
};

__global__ __launch_bounds__(512, 2) void gemm8p(const bf16* __restrict__ A, GemmArgs args) {
    __shared__ char lds[131072];
    constexpr int NT = D_ / 64;   // 32 K-tiles
    const int z = blockIdx.z;
    const int t = threadIdx.x;

    if (z == 3) {
        const int flat = blockIdx.y * 8 + blockIdx.x;
        const int* src = args.wo_src + (size_t)flat * 65536;
        bf16* dst = args.wo_dst + (size_t)flat * 65536;
#pragma unroll
        for (int it = 0; it < 16; ++it) {
            int off = it * 4096 + t * 8;
            int4 v0 = *(const int4*)(src + off);
            int4 v1 = *(const int4*)(src + off + 4);
            bf16x8 o;
            o[0] = (bf16)(float)v0.x; o[1] = (bf16)(float)v0.y;
            o[2] = (bf16)(float)v0.z; o[3] = (bf16)(float)v0.w;
            o[4] = (bf16)(float)v1.x; o[5] = (bf16)(float)v1.y;
            o[6] = (bf16)(float)v1.z; o[7] = (bf16)(float)v1.w;
            *(bf16x8*)(dst + off) = o;
        }
        return;
    }

    const bf16* __restrict__ Wz = args.W[z];
    const float* __restrict__ Sc = args.Sc[z];
    const int mode = args.mode[z];
    const int w = t >> 6, l = t & 63;
    const int wr = w >> 2, wc = w & 3;
    const int m0 = blockIdx.y * 256, n0 = blockIdx.x * 256;
    const int hi = l >> 4, lo = l & 15;

    const int r8 = l >> 3;
    const int ce = ((l & 7) ^ (r8 & 7)) * 8;   // pre-swizzled source column
    const bf16* Ag = A  + (size_t)(m0 + w * 8 + r8) * D_ + ce;
    const bf16* Bg = Wz + (size_t)(n0 + w * 8 + r8) * D_ + ce;

    auto stage = [&](int kt, int q) {
        if (kt >= NT) return;
        const bf16* g = (q < 2 ? Ag : Bg) + (size_t)((q & 1) * 128) * D_ + (size_t)kt * 64;
        char* d = lds + ((kt & 1) ? 65536 : 0) + q * 16384 + w * 1024;
        gload_lds16((const void*)g, (void*)d);
        gload_lds16((const void*)(g + (size_t)64 * D_), (void*)(d + 8192));
    };

    f32x4 acc[8][4] = {};

    stage(0, 0); stage(0, 1); stage(0, 2); stage(0, 3);
    stage(1, 2); stage(1, 0);
    asm volatile("s_waitcnt vmcnt(4)" ::: "memory");
    asm volatile("s_barrier" ::: "memory");

    for (int kt = 0; kt < NT; ++kt) {
        const char* Pb = lds + ((kt & 1) ? 65536 : 0);
        const char* As = Pb;
        const char* Bs = Pb + 32768;
        bf16x8 a[4][2], b01[2][2], b23[2][2];

        auto rdA = [&](int mi, int kk) -> bf16x8 {
            int row = wr * 128 + mi * 16 + lo;
            return *(const bf16x8*)(As + row * 128 + ((kk * 64 + hi * 16) ^ ((row & 7) << 4)));
        };
        auto rdB = [&](int ni, int kk) -> bf16x8 {
            int row = wc * 64 + ni * 16 + lo;
            return *(const bf16x8*)(Bs + row * 128 + ((kk * 64 + hi * 16) ^ ((row & 7) << 4)));
        };

        // ---- p0: A0-3 x B0-1 ----
#pragma unroll
        for (int mi = 0; mi < 4; ++mi) { a[mi][0] = rdA(mi, 0); a[mi][1] = rdA(mi, 1); }
#pragma unroll
        for (int ni = 0; ni < 2; ++ni) { b01[ni][0] = rdB(ni, 0); b01[ni][1] = rdB(ni, 1); }
        stage(kt + 1, 1);
        asm volatile("s_barrier" ::: "memory");
        asm volatile("s_waitcnt lgkmcnt(0)" ::: "memory");
        __builtin_amdgcn_sched_barrier(0);
        __builtin_amdgcn_s_setprio(1);
#pragma unroll
        for (int mi = 0; mi < 4; ++mi)
#pragma unroll
            for (int ni = 0; ni < 2; ++ni)
#pragma unroll
                for (int kk = 0; kk < 2; ++kk)
                    acc[mi][ni] = __builtin_amdgcn_mfma_f32_16x16x32_bf16(a[mi][kk], b01[ni][kk], acc[mi][ni], 0, 0, 0);
        __builtin_amdgcn_s_setprio(0);
        asm volatile("s_barrier" ::: "memory");

        // ---- p1: A0-3 x B2-3 ----
#pragma unroll
        for (int ni = 0; ni < 2; ++ni) { b23[ni][0] = rdB(2 + ni, 0); b23[ni][1] = rdB(2 + ni, 1); }
        stage(kt + 1, 3);
        asm volatile("s_barrier" ::: "memory");
        asm volatile("s_waitcnt lgkmcnt(0)" ::: "memory");
        __builtin_amdgcn_sched_barrier(0);
        __builtin_amdgcn_s_setprio(1);
#pragma unroll
        for (int mi = 0; mi < 4; ++mi)
#pragma unroll
            for (int ni = 0; ni < 2; ++ni)
#pragma unroll
                for (int kk = 0; kk < 2; ++kk)
                    acc[mi][2 + ni] = __builtin_amdgcn_mfma_f32_16x16x32_bf16(a[mi][kk], b23[ni][kk], acc[mi][2 + ni], 0, 0, 0);
        __builtin_amdgcn_s_setprio(0);
        asm volatile("s_barrier" ::: "memory");

        // ---- p2: A4-7 x B2-3 ----
#pragma unroll
        for (int mi = 0; mi < 4; ++mi) { a[mi][0] = rdA(4 + mi, 0); a[mi][1] = rdA(4 + mi, 1); }
        stage(kt + 2, 2);
        asm volatile("s_barrier" ::: "memory");
        asm volatile("s_waitcnt lgkmcnt(0)" ::: "memory");
        __builtin_amdgcn_sched_barrier(0);
        __builtin_amdgcn_s_setprio(1);
#pragma unroll
        for (int mi = 0; mi < 4; ++mi)
#pragma unroll
            for (int ni = 0; ni < 2; ++ni)
#pragma unroll
                for (int kk = 0; kk < 2; ++kk)
                    acc[4 + mi][2 + ni] = __builtin_amdgcn_mfma_f32_16x16x32_bf16(a[mi][kk], b23[ni][kk], acc[4 + mi][2 + ni], 0, 0, 0);
        __builtin_amdgcn_s_setprio(0);
        asm volatile("s_barrier" ::: "memory");

        // ---- p3: A4-7 x B0-1 ----
        stage(kt + 2, 0);
        asm volatile("s_barrier" ::: "memory");
        __builtin_amdgcn_sched_barrier(0);
        __builtin_amdgcn_s_setprio(1);
#pragma unroll
        for (int mi = 0; mi < 4; ++mi)
#pragma unroll
            for (int ni = 0; ni < 2; ++ni)
#pragma unroll
                for (int kk = 0; kk < 2; ++kk)
                    acc[4 + mi][ni] = __builtin_amdgcn_mfma_f32_16x16x32_bf16(a[mi][kk], b01[ni][kk], acc[4 + mi][ni], 0, 0, 0);
        __builtin_amdgcn_s_setprio(0);
        if (kt < NT - 2) asm volatile("s_waitcnt vmcnt(4)" ::: "memory");
        else             asm volatile("s_waitcnt vmcnt(0)" ::: "memory");
        asm volatile("s_barrier" ::: "memory");
    }

#pragma unroll
    for (int ni = 0; ni < 4; ++ni) {
        const int n = n0 + wc * 64 + ni * 16 + lo;
        const float scv = Sc[n];
#pragma unroll
        for (int mi = 0; mi < 8; ++mi) {
            const int mb = m0 + wr * 128 + mi * 16 + hi * 4;
            if (mode == 1) {
                bf16x4 pk;
#pragma unroll
                for (int r = 0; r < 4; ++r) pk[r] = (bf16)(acc[mi][ni][r] * scv);
                const int bb = mb >> 10, s = mb & 1023, hh = n >> 7, dh = n & 127;
                *(bf16x4*)(((bf16*)args.O[z]) + (((size_t)(bb * H_ + hh)) * DH_ + dh) * S_ + s) = pk;
            } else {
#pragma unroll
                for (int r = 0; r < 4; ++r)
                    ((bf16*)args.O[z])[(size_t)(mb + r) * D_ + n] = (bf16)(acc[mi][ni][r] * scv);
            }
        }
    }
}

// ---------------- O-proj GEMM: BM=BN=128, 4 waves, 2-phase counted vmcnt ----------------
__global__ __launch_bounds__(256, 2) void gemmO(const bf16* __restrict__ A, const bf16* __restrict__ W,
                                                const float* __restrict__ Sc, float* __restrict__ O) {
    __shared__ char lds[65536];
    constexpr int NT = D_ / 64;
    const int t = threadIdx.x;
    const int w = t >> 6, l = t & 63;
    const int wr = w >> 1, wc = w & 1;
    const int m0 = blockIdx.y * 128, n0 = blockIdx.x * 128;
    const int hi = l >> 4, lo = l & 15;

    const int r8 = l >> 3;
    const int ce = ((l & 7) ^ (r8 & 7)) * 8;
    const bf16* Ag = A + (size_t)(m0 + w * 8 + r8) * D_ + ce;
    const bf16* Bg = W + (size_t)(n0 + w * 8 + r8) * D_ + ce;

    auto stage = [&](int kt) {
        char* d = lds + (kt & 1) * 32768 + w * 1024;
        const bf16* ga = Ag + (size_t)kt * 64;
        const bf16* gb = Bg + (size_t)kt * 64;
#pragma unroll
        for (int j = 0; j < 4; ++j) {
            gload_lds16((const void*)(ga + (size_t)j * 32 * D_), (void*)(d + j * 4096));
            gload_lds16((const void*)(gb + (size_t)j * 32 * D_), (void*)(d + 16384 + j * 4096));
        }
    };

    f32x4 acc[4][4] = {};
    stage(0);
    for (int kt = 0; kt < NT; ++kt) {
        const char* cur = lds + (kt & 1) * 32768;
        if (kt + 1 < NT) {
            stage(kt + 1);
            asm volatile("s_waitcnt vmcnt(8)" ::: "memory");
        } else {
            asm volatile("s_waitcnt vmcnt(0)" ::: "memory");
        }
        asm volatile("s_barrier" ::: "memory");

        bf16x8 a[4][2], b[4][2];
#pragma unroll
        for (int mi = 0; mi < 4; ++mi)
#pragma unroll
            for (int kk = 0; kk < 2; ++kk) {
                int row = wr * 64 + mi * 16 + lo;
                a[mi][kk] = *(const bf16x8*)(cur + row * 128 + ((kk * 64 + hi * 16) ^ ((row & 7) << 4)));
            }
#pragma unroll
        for (int ni = 0; ni < 4; ++ni)
#pragma unroll
            for (int kk = 0; kk < 2; ++kk) {
                int row = wc * 64 + ni * 16 + lo;
                b[ni][kk] = *(const bf16x8*)(cur + 16384 + row * 128 + ((kk * 64 + hi * 16) ^ ((row & 7) << 4)));
            }
        __builtin_amdgcn_s_setprio(1);
#pragma unroll
        for (int mi = 0; mi < 4; ++mi)
#pragma unroll
            for (int ni = 0; ni < 4; ++ni)
#pragma unroll
                for (int kk = 0; kk < 2; ++kk)
                    acc[mi][ni] = __builtin_amdgcn_mfma_f32_16x16x32_bf16(a[mi][kk], b[ni][kk], acc[mi][ni], 0, 0, 0);
        __builtin_amdgcn_s_setprio(0);
        asm volatile("s_barrier" ::: "memory");
    }

#pragma unroll
    for (int ni = 0; ni < 4; ++ni) {
        const int n = n0 + wc * 64 + ni * 16 + lo;
        const float scv = Sc[n];
#pragma unroll
        for (int mi = 0; mi < 4; ++mi) {
            const int mb = m0 + wr * 64 + mi * 16 + hi * 4;
#pragma unroll
            for (int r = 0; r < 4; ++r)
                O[(size_t)(mb + r) * D_ + n] = acc[mi][ni][r] * scv;
        }
    }
}

// ---------------- RMSNorm + RoPE, q+k merged per block, transpose to [B,H,S,Dh] ----------------
__global__ __launch_bounds__(256) void rope_norm(const bf16* __restrict__ qr, const bf16* __restrict__ kr,
                                                 const float* __restrict__ qn, const float* __restrict__ kn,
                                                 const float* __restrict__ cosT, const float* __restrict__ sinT,
                                                 bf16* __restrict__ qOut, bf16* __restrict__ kOut) {
    const int row = blockIdx.x;           // b*S + s
    const int b = row >> 10, s = row & 1023;
    const int t = threadIdx.x;
    __shared__ float xs[D_];
    __shared__ float red[4];

    const int h = t >> 4;
    const int dh0 = (t & 15) * 8;
    float cv[8], sv8[8];
#pragma unroll
    for (int j = 0; j < 8; ++j) {
        cv[j]  = cosT[s * DH_ + dh0 + j];
        sv8[j] = sinT[s * DH_ + dh0 + j];
    }

#pragma unroll
    for (int which = 0; which < 2; ++which) {
        const bf16* src = which ? kr : qr;
        const float* nw = which ? kn : qn;
        bf16* dst = which ? kOut : qOut;

        bf16x8 v = *(const bf16x8*)(src + (size_t)row * D_ + t * 8);
        float x[8]; float ss = 0.f;
#pragma unroll
        for (int j = 0; j < 8; ++j) { x[j] = (float)v[j]; ss += x[j] * x[j]; xs[t * 8 + j] = x[j]; }
#pragma unroll
        for (int msk = 32; msk; msk >>= 1) ss += __shfl_xor(ss, msk, 64);
        if ((t & 63) == 0) red[t >> 6] = ss;
        __syncthreads();
        const float inv = rsqrtf((red[0] + red[1] + red[2] + red[3]) / (float)D_ + EPSF);

        bf16x8 o;
#pragma unroll
        for (int j = 0; j < 8; ++j) {
            int dd = dh0 + j;
            int d = h * 128 + dd;
            int pd = (dd < 64) ? d + 64 : d - 64;
            float xn = x[j] * inv * nw[d];
            float xp = xs[pd] * inv * nw[pd];
            float rot = (dd < 64) ? -xp : xp;
            o[j] = (bf16)(xn * cv[j] + rot * sv8[j]);
        }
        *(bf16x8*)(dst + (((size_t)(b * H_ + h)) * S_ + s) * DH_ + dh0) = o;
        if (which == 0) __syncthreads();   // protect xs/red before reuse
    }
}

// ---------------- flash attention (round-7 known-good + defer-max) ----------------
// Q,K: [B,H,S,Dh] ; VT: [B,H,Dh,S] ; Out: [B*S, D] bf16
__global__ __launch_bounds__(256) void flash(const bf16* __restrict__ Q, const bf16* __restrict__ Kb,
                                             const bf16* __restrict__ VTb, const int* __restrict__ lengths,
                                             bf16* __restrict__ Out) {
    __shared__ bf16 Qs[64 * 128];
    __shared__ bf16 Ks[64 * 128];
    __shared__ bf16 Vt[128 * 64];
    __shared__ bf16 Ps[4][16 * 64];
    const int t = threadIdx.x, w = t >> 6, l = t & 63;
    const int bh = blockIdx.y;
    const int b = bh >> 4;
    const int q0 = blockIdx.x * 64;
    const int L = lengths[b];
    const size_t base = (size_t)bh * S_ * DH_;
    const size_t vbase = (size_t)bh * DH_ * S_;
    const int hi = l >> 4, lo = l & 15;
    const int swz = (lo & 7) << 3;

    {
        const bf16* src = Q + base + (size_t)q0 * DH_;
#pragma unroll
        for (int i = 0; i < 4; ++i) {
            int r = (w * 4 + i) * 4 + (l >> 4);
            int sb = ((l & 15) * 16) ^ ((r & 7) << 4);
            gload_lds16((const void*)(src + (size_t)r * DH_ + (sb >> 1)), (void*)(Qs + (w * 4 + i) * 512));
        }
    }

    f32x4 O[8] = {};
    float mrow[4], lrow[4];
#pragma unroll
    for (int r = 0; r < 4; ++r) { mrow[r] = -1e30f; lrow[r] = 0.f; }
    const int nt = (L + 63) >> 6;
    const float sscale = 0.08838834764831843f;

    for (int kt = 0; kt < nt; ++kt) {
        const int k0 = kt * 64;
        __syncthreads();
        {
            const bf16* ksrc = Kb + base + (size_t)k0 * DH_;
#pragma unroll
            for (int i = 0; i < 4; ++i) {
                int r = (w * 4 + i) * 4 + (l >> 4);
                int sb = ((l & 15) * 16) ^ ((r & 7) << 4);
                gload_lds16((const void*)(ksrc + (size_t)r * DH_ + (sb >> 1)), (void*)(Ks + (w * 4 + i) * 512));
            }
        }
        {
            const bf16* vsrc = VTb + vbase + k0;
#pragma unroll
            for (int i = 0; i < 4; ++i) {
                int d = (w * 4 + i) * 8 + (l >> 3);
                int sb = ((l & 7) * 16) ^ ((d & 7) << 4);
                gload_lds16((const void*)(vsrc + (size_t)d * S_ + (sb >> 1)), (void*)(Vt + (w * 4 + i) * 512));
            }
        }
        __syncthreads();

        f32x4 sc[4] = {};
#pragma unroll
        for (int kk = 0; kk < 4; ++kk) {
            const int ko = kk * 32 + hi * 8;
            bf16x8 aq = *(const bf16x8*)(Qs + (w * 16 + lo) * 128 + (ko ^ swz));
#pragma unroll
            for (int ni = 0; ni < 4; ++ni) {
                bf16x8 bk = *(const bf16x8*)(Ks + (ni * 16 + lo) * 128 + (ko ^ swz));
                sc[ni] = __builtin_amdgcn_mfma_f32_16x16x32_bf16(aq, bk, sc[ni], 0, 0, 0);
            }
        }

        float p[4][4];
#pragma unroll
        for (int r = 0; r < 4; ++r) {
            float sv[4]; float vmax = -1e30f;
#pragma unroll
            for (int ni = 0; ni < 4; ++ni) {
                int kg = k0 + ni * 16 + lo;
                float vv = sc[ni][r] * sscale;
                if (kg >= L) vv = -1e30f;
                sv[ni] = vv;
                vmax = fmaxf(vmax, vv);
            }
#pragma unroll
            for (int msk = 1; msk < 16; msk <<= 1) vmax = fmaxf(vmax, __shfl_xor(vmax, msk, 64));
            // defer-max (T13, THR=8): avoid O-rescale when max growth is small
            float mnew, corr;
            if (vmax <= mrow[r] + 8.f) { mnew = mrow[r]; corr = 1.f; }
            else { mnew = vmax; corr = __expf(mrow[r] - mnew); }
            float rs = 0.f;
#pragma unroll
            for (int ni = 0; ni < 4; ++ni) { float pv = __expf(sv[ni] - mnew); p[r][ni] = pv; rs += pv; }
#pragma unroll
            for (int msk = 1; msk < 16; msk <<= 1) rs += __shfl_xor(rs, msk, 64);
            lrow[r] = lrow[r] * corr + rs;
            mrow[r] = mnew;
            if (corr != 1.f) {
#pragma unroll
                for (int di = 0; di < 8; ++di) O[di][r] *= corr;
            }
        }

#pragma unroll
        for (int r = 0; r < 4; ++r) {
            int prow = hi * 4 + r;
#pragma unroll
            for (int ni = 0; ni < 4; ++ni)
                Ps[w][prow * 64 + (((ni * 16 + lo)) ^ ((prow & 7) << 3))] = (bf16)p[r][ni];
        }

#pragma unroll
        for (int kk = 0; kk < 2; ++kk) {
            const int ko = kk * 32 + hi * 8;
            bf16x8 ap = *(const bf16x8*)(&Ps[w][lo * 64 + (ko ^ swz)]);
#pragma unroll
            for (int di = 0; di < 8; ++di) {
                bf16x8 bv = *(const bf16x8*)(Vt + (di * 16 + lo) * 64 + (ko ^ swz));
                O[di] = __builtin_amdgcn_mfma_f32_16x16x32_bf16(ap, bv, O[di], 0, 0, 0);
            }
        }
    }

    const int h = bh & 15;
#pragma unroll
    for (int r = 0; r < 4; ++r) {
        float invl = 1.0f / lrow[r];
        int qrow = q0 + w * 16 + hi * 4 + r;
        bf16* orow = Out + (size_t)(b * S_ + qrow) * D_ + h * DH_;
#pragma unroll
        for (int di = 0; di < 8; ++di)
            orow[di * 16 + lo] = (bf16)(O[di][r] * invl);
    }
}

// ---------------- launch ----------------
extern "C" void kernel_launch(void* const* d_in, const int* in_sizes, int n_in,
                              void* d_out, int out_size, void* d_ws, size_t ws_size,
                              hipStream_t stream) {
    const float* x    = (const float*)d_in[0];
    const float* wq_s = (const float*)d_in[1];
    const float* wk_s = (const float*)d_in[2];
    const float* wv_s = (const float*)d_in[3];
    const float* wo_s = (const float*)d_in[4];
    const float* qn   = (const float*)d_in[5];
    const float* kn   = (const float*)d_in[6];
    const float* cosT = (const float*)d_in[7];
    const float* sinT = (const float*)d_in[8];
    const int* wq = (const int*)d_in[9];
    const int* wk = (const int*)d_in[10];
    const int* wv = (const int*)d_in[11];
    const int* wo = (const int*)d_in[12];
    const int* lengths = (const int*)d_in[13];
    float* out = (float*)d_out;

    char* ws = (char*)d_ws;
    const size_t SLOT = (size_t)M_ * D_ * sizeof(bf16);  // 8 MiB
    bf16* xb   = (bf16*)(ws);
    bf16* wqb  = (bf16*)(ws + 1 * SLOT);
    bf16* wkb  = (bf16*)(ws + 2 * SLOT);
    bf16* wvb  = (bf16*)(ws + 3 * SLOT);
    bf16* wob  = (bf16*)(ws + 4 * SLOT);
    bf16* qr   = (bf16*)(ws + 5 * SLOT);
    bf16* kr   = (bf16*)(ws + 6 * SLOT);
    bf16* qb2  = (bf16*)(ws + 7 * SLOT);
    bf16* kb2  = (bf16*)(ws + 8 * SLOT);
    bf16* vb2  = (bf16*)(ws + 9 * SLOT);  // V^T layout [B,H,Dh,S]
    bf16* attnb = qr;   // reuse after rope_norm

    const int NW = D_ * D_;  // 4194304
    ConvArgs ca;
    ca.s[0] = x;  ca.d[0] = xb;
    ca.s[1] = wq; ca.d[1] = wqb;
    ca.s[2] = wk; ca.d[2] = wkb;
    ca.s[3] = wv; ca.d[3] = wvb;
    conv_all<<<dim3(NW / 2048, 4), dim3(256), 0, stream>>>(ca, NW);

    GemmArgs ga;
    ga.W[0] = wqb; ga.W[1] = wkb; ga.W[2] = wvb;
    ga.Sc[0] = wq_s; ga.Sc[1] = wk_s; ga.Sc[2] = wv_s;
    ga.O[0] = qr; ga.O[1] = kr; ga.O[2] = vb2;
    ga.mode[0] = 2; ga.mode[1] = 2; ga.mode[2] = 1;
    ga.wo_src = wo; ga.wo_dst = wob;
    gemm8p<<<dim3(D_ / 256, M_ / 256, 4), dim3(512), 0, stream>>>(xb, ga);

    rope_norm<<<dim3(M_), dim3(256), 0, stream>>>(qr, kr, qn, kn, cosT, sinT, qb2, kb2);

    flash<<<dim3(S_ / 64, B_ * H_, 1), dim3(256), 0, stream>>>(qb2, kb2, vb2, lengths, attnb);

    gemmO<<<dim3(D_ / 128, M_ / 128), dim3(256), 0, stream>>>(attnb, wob, wo_s, out);
}

// Round 10
// 148.739 us; speedup vs baseline: 1.1109x; 1.0927x over previous
//
#include <hip/hip_runtime.h>
#include <stdint.h>

typedef __bf16 bf16;
typedef bf16 bf16x8 __attribute__((ext_vector_type(8)));
typedef bf16 bf16x4 __attribute__((ext_vector_type(4)));
typedef float f32x4 __attribute__((ext_vector_type(4)));

#define B_   2
#define S_   1024
#define D_   2048
#define H_   16
#define DH_  128
#define M_   (B_*S_)
#define EPSF 1e-6f

__device__ __forceinline__ void gload_lds16(const void* g, void* l) {
    __builtin_amdgcn_global_load_lds(
        (const __attribute__((address_space(1))) void*)g,
        (__attribute__((address_space(3))) void*)l,
        16, 0, 0);
}

// ---------------- fused conversion kernel (x, wq, wk, wv, wo) ----------------
struct ConvArgs {
    const void* s[5];
    bf16* d[5];
};

__global__ __launch_bounds__(256) void conv_all(ConvArgs a, int n) {
    const int z = blockIdx.y;
    const int i = (blockIdx.x * 256 + threadIdx.x) * 8;
    if (i + 8 > n) return;
    bf16x8 o;
    if (z == 0) {
        const float* src = (const float*)a.s[0];
        float4 v0 = *(const float4*)(src + i);
        float4 v1 = *(const float4*)(src + i + 4);
        o[0] = (bf16)v0.x; o[1] = (bf16)v0.y; o[2] = (bf16)v0.z; o[3] = (bf16)v0.w;
        o[4] = (bf16)v1.x; o[5] = (bf16)v1.y; o[6] = (bf16)v1.z; o[7] = (bf16)v1.w;
    } else {
        const int* src = (const int*)a.s[z];
        int4 v0 = *(const int4*)(src + i);
        int4 v1 = *(const int4*)(src + i + 4);
        o[0] = (bf16)(float)v0.x; o[1] = (bf16)(float)v0.y;
        o[2] = (bf16)(float)v0.z; o[3] = (bf16)(float)v0.w;
        o[4] = (bf16)(float)v1.x; o[5] = (bf16)(float)v1.y;
        o[6] = (bf16)(float)v1.z; o[7] = (bf16)(float)v1.w;
    }
    *(bf16x8*)(a.d[z] + i) = o;
}

// ---------------- QKV GEMM: 256x192 tiles over concatenated W [6144 x 2048], 256 blocks (full fill) ----------------
// C[m,n] = sum_k A[m,k]*Wcat[n,k]*scale; z = n>>11 selects {q,k,v}; q/k row-major bf16, v scattered to V^T.
struct QKVArgs {
    const float* Sc[3];
    bf16* qO; bf16* kO; bf16* vO;
};

__global__ __launch_bounds__(512, 2) void gemmQKV(const bf16* __restrict__ A, const bf16* __restrict__ Wcat,
                                                  QKVArgs args) {
    __shared__ char lds[114688];          // 2 x (A 32KB + B 24KB)
    constexpr int NT = D_ / 64;           // 32 K-tiles
    constexpr int BUF = 57344;
    const int t = threadIdx.x;
    const int w = t >> 6, l = t & 63;
    const int wr = w >> 2, wc = w & 3;
    const int m0 = blockIdx.y * 256, n0 = blockIdx.x * 192;
    const int hi = l >> 4, lo = l & 15;

    const int r8 = l >> 3;
    const int ce = ((l & 7) ^ (r8 & 7)) * 8;   // pre-swizzled source column
    const bf16* Ag = A    + (size_t)(m0 + w * 8 + r8) * D_ + ce;
    const bf16* Bg = Wcat + (size_t)(n0 + w * 8 + r8) * D_ + ce;

    // A half: rows half*128..+127 (2 loads); B: 192 rows (3 loads)
    auto stageA = [&](int kt, int half) {
        if (kt >= NT) return;
        const bf16* g = Ag + (size_t)(half * 128) * D_ + (size_t)kt * 64;
        char* d = lds + (kt & 1) * BUF + half * 16384 + w * 1024;
        gload_lds16((const void*)g, (void*)d);
        gload_lds16((const void*)(g + (size_t)64 * D_), (void*)(d + 8192));
    };
    auto stageB = [&](int kt) {
        if (kt >= NT) return;
        const bf16* g = Bg + (size_t)kt * 64;
        char* d = lds + (kt & 1) * BUF + 32768 + w * 1024;
        gload_lds16((const void*)g, (void*)d);
        gload_lds16((const void*)(g + (size_t)64 * D_), (void*)(d + 8192));
        gload_lds16((const void*)(g + (size_t)128 * D_), (void*)(d + 16384));
    };

    f32x4 acc[8][3] = {};

    // prologue: tile0 complete (7 oldest), then tile1.B, tile1.A1
    stageA(0, 0); stageA(0, 1); stageB(0);
    stageB(1); stageA(1, 0);
    asm volatile("s_waitcnt vmcnt(5)" ::: "memory");
    asm volatile("s_barrier" ::: "memory");

    for (int kt = 0; kt < NT; ++kt) {
        const char* Pb = lds + (kt & 1) * BUF;
        const char* As = Pb;
        const char* Bs = Pb + 32768;
        bf16x8 a[4][2], b0[2], b1[2], b2[2];

        auto rdA = [&](int mi, int kk) -> bf16x8 {
            int row = wr * 128 + mi * 16 + lo;
            return *(const bf16x8*)(As + row * 128 + ((kk * 64 + hi * 16) ^ ((row & 7) << 4)));
        };
        auto rdB = [&](int ni, int kk) -> bf16x8 {
            int row = wc * 48 + ni * 16 + lo;
            return *(const bf16x8*)(Bs + row * 128 + ((kk * 64 + hi * 16) ^ ((row & 7) << 4)));
        };

        // ---- p0: A0-3 x B0,B1 (16 MFMA) ----
#pragma unroll
        for (int mi = 0; mi < 4; ++mi) { a[mi][0] = rdA(mi, 0); a[mi][1] = rdA(mi, 1); }
        b0[0] = rdB(0, 0); b0[1] = rdB(0, 1);
        b1[0] = rdB(1, 0); b1[1] = rdB(1, 1);
        stageA(kt + 1, 1);
        asm volatile("s_barrier" ::: "memory");
        asm volatile("s_waitcnt lgkmcnt(0)" ::: "memory");
        __builtin_amdgcn_sched_barrier(0);
        __builtin_amdgcn_s_setprio(1);
#pragma unroll
        for (int mi = 0; mi < 4; ++mi)
#pragma unroll
            for (int kk = 0; kk < 2; ++kk) {
                acc[mi][0] = __builtin_amdgcn_mfma_f32_16x16x32_bf16(a[mi][kk], b0[kk], acc[mi][0], 0, 0, 0);
                acc[mi][1] = __builtin_amdgcn_mfma_f32_16x16x32_bf16(a[mi][kk], b1[kk], acc[mi][1], 0, 0, 0);
            }
        __builtin_amdgcn_s_setprio(0);
        asm volatile("s_barrier" ::: "memory");

        // ---- p1: A0-3 x B2 (8 MFMA) ----
        b2[0] = rdB(2, 0); b2[1] = rdB(2, 1);
        asm volatile("s_barrier" ::: "memory");
        asm volatile("s_waitcnt lgkmcnt(0)" ::: "memory");
        __builtin_amdgcn_sched_barrier(0);
        __builtin_amdgcn_s_setprio(1);
#pragma unroll
        for (int mi = 0; mi < 4; ++mi)
#pragma unroll
            for (int kk = 0; kk < 2; ++kk)
                acc[mi][2] = __builtin_amdgcn_mfma_f32_16x16x32_bf16(a[mi][kk], b2[kk], acc[mi][2], 0, 0, 0);
        __builtin_amdgcn_s_setprio(0);
        asm volatile("s_barrier" ::: "memory");

        // ---- p2: A4-7 x B1,B2 (16 MFMA); B-region free after p1 -> stage (T+2).B ----
#pragma unroll
        for (int mi = 0; mi < 4; ++mi) { a[mi][0] = rdA(4 + mi, 0); a[mi][1] = rdA(4 + mi, 1); }
        stageB(kt + 2);
        asm volatile("s_barrier" ::: "memory");
        asm volatile("s_waitcnt lgkmcnt(0)" ::: "memory");
        __builtin_amdgcn_sched_barrier(0);
        __builtin_amdgcn_s_setprio(1);
#pragma unroll
        for (int mi = 0; mi < 4; ++mi)
#pragma unroll
            for (int kk = 0; kk < 2; ++kk) {
                acc[4 + mi][1] = __builtin_amdgcn_mfma_f32_16x16x32_bf16(a[mi][kk], b1[kk], acc[4 + mi][1], 0, 0, 0);
                acc[4 + mi][2] = __builtin_amdgcn_mfma_f32_16x16x32_bf16(a[mi][kk], b2[kk], acc[4 + mi][2], 0, 0, 0);
            }
        __builtin_amdgcn_s_setprio(0);
        asm volatile("s_barrier" ::: "memory");

        // ---- p3: A4-7 x B0 (8 MFMA); A1-region free after p0 -> stage (T+2).A1 ----
        stageA(kt + 2, 0);
        asm volatile("s_barrier" ::: "memory");
        __builtin_amdgcn_sched_barrier(0);
        __builtin_amdgcn_s_setprio(1);
#pragma unroll
        for (int mi = 0; mi < 4; ++mi)
#pragma unroll
            for (int kk = 0; kk < 2; ++kk)
                acc[4 + mi][0] = __builtin_amdgcn_mfma_f32_16x16x32_bf16(a[mi][kk], b0[kk], acc[4 + mi][0], 0, 0, 0);
        __builtin_amdgcn_s_setprio(0);
        if (kt < NT - 2) asm volatile("s_waitcnt vmcnt(5)" ::: "memory");
        else             asm volatile("s_waitcnt vmcnt(0)" ::: "memory");
        asm volatile("s_barrier" ::: "memory");
    }

    // epilogue: n -> z = n>>11 (0:q, 1:k, 2:v)
#pragma unroll
    for (int ni = 0; ni < 3; ++ni) {
        const int n = n0 + wc * 48 + ni * 16 + lo;
        const int z = n >> 11, col = n & 2047;
        const float scv = args.Sc[z][col];
#pragma unroll
        for (int mi = 0; mi < 8; ++mi) {
            const int mb = m0 + wr * 128 + mi * 16 + hi * 4;
            if (z == 2) {
                bf16x4 pk;
#pragma unroll
                for (int r = 0; r < 4; ++r) pk[r] = (bf16)(acc[mi][ni][r] * scv);
                const int bb = mb >> 10, s = mb & 1023, hh = col >> 7, dh = col & 127;
                *(bf16x4*)(args.vO + (((size_t)(bb * H_ + hh)) * DH_ + dh) * S_ + s) = pk;
            } else {
                bf16* dst = (z == 0 ? args.qO : args.kO);
#pragma unroll
                for (int r = 0; r < 4; ++r)
                    dst[(size_t)(mb + r) * D_ + col] = (bf16)(acc[mi][ni][r] * scv);
            }
        }
    }
}

// ---------------- O-proj GEMM: BM=BN=128, 4 waves, 2-phase counted vmcnt ----------------
__global__ __launch_bounds__(256, 2) void gemmO(const bf16* __restrict__ A, const bf16* __restrict__ W,
                                                const float* __restrict__ Sc, float* __restrict__ O) {
    __shared__ char lds[65536];
    constexpr int NT = D_ / 64;
    const int t = threadIdx.x;
    const int w = t >> 6, l = t & 63;
    const int wr = w >> 1, wc = w & 1;
    const int m0 = blockIdx.y * 128, n0 = blockIdx.x * 128;
    const int hi = l >> 4, lo = l & 15;

    const int r8 = l >> 3;
    const int ce = ((l & 7) ^ (r8 & 7)) * 8;
    const bf16* Ag = A + (size_t)(m0 + w * 8 + r8) * D_ + ce;
    const bf16* Bg = W + (size_t)(n0 + w * 8 + r8) * D_ + ce;

    auto stage = [&](int kt) {
        char* d = lds + (kt & 1) * 32768 + w * 1024;
        const bf16* ga = Ag + (size_t)kt * 64;
        const bf16* gb = Bg + (size_t)kt * 64;
#pragma unroll
        for (int j = 0; j < 4; ++j) {
            gload_lds16((const void*)(ga + (size_t)j * 32 * D_), (void*)(d + j * 4096));
            gload_lds16((const void*)(gb + (size_t)j * 32 * D_), (void*)(d + 16384 + j * 4096));
        }
    };

    f32x4 acc[4][4] = {};
    stage(0);
    for (int kt = 0; kt < NT; ++kt) {
        const char* cur = lds + (kt & 1) * 32768;
        if (kt + 1 < NT) {
            stage(kt + 1);
            asm volatile("s_waitcnt vmcnt(8)" ::: "memory");
        } else {
            asm volatile("s_waitcnt vmcnt(0)" ::: "memory");
        }
        asm volatile("s_barrier" ::: "memory");

        bf16x8 a[4][2], b[4][2];
#pragma unroll
        for (int mi = 0; mi < 4; ++mi)
#pragma unroll
            for (int kk = 0; kk < 2; ++kk) {
                int row = wr * 64 + mi * 16 + lo;
                a[mi][kk] = *(const bf16x8*)(cur + row * 128 + ((kk * 64 + hi * 16) ^ ((row & 7) << 4)));
            }
#pragma unroll
        for (int ni = 0; ni < 4; ++ni)
#pragma unroll
            for (int kk = 0; kk < 2; ++kk) {
                int row = wc * 64 + ni * 16 + lo;
                b[ni][kk] = *(const bf16x8*)(cur + 16384 + row * 128 + ((kk * 64 + hi * 16) ^ ((row & 7) << 4)));
            }
        __builtin_amdgcn_s_setprio(1);
#pragma unroll
        for (int mi = 0; mi < 4; ++mi)
#pragma unroll
            for (int ni = 0; ni < 4; ++ni)
#pragma unroll
                for (int kk = 0; kk < 2; ++kk)
                    acc[mi][ni] = __builtin_amdgcn_mfma_f32_16x16x32_bf16(a[mi][kk], b[ni][kk], acc[mi][ni], 0, 0, 0);
        __builtin_amdgcn_s_setprio(0);
        asm volatile("s_barrier" ::: "memory");
    }

#pragma unroll
    for (int ni = 0; ni < 4; ++ni) {
        const int n = n0 + wc * 64 + ni * 16 + lo;
        const float scv = Sc[n];
#pragma unroll
        for (int mi = 0; mi < 4; ++mi) {
            const int mb = m0 + wr * 64 + mi * 16 + hi * 4;
#pragma unroll
            for (int r = 0; r < 4; ++r)
                O[(size_t)(mb + r) * D_ + n] = acc[mi][ni][r] * scv;
        }
    }
}

// ---------------- RMSNorm + RoPE + transpose to [B,H,S,Dh] (round-7 known-good) ----------------
__global__ __launch_bounds__(256) void rope_norm(const bf16* __restrict__ qr, const bf16* __restrict__ kr,
                                                 const float* __restrict__ qn, const float* __restrict__ kn,
                                                 const float* __restrict__ cosT, const float* __restrict__ sinT,
                                                 bf16* __restrict__ qOut, bf16* __restrict__ kOut) {
    const int which = blockIdx.z;
    const bf16* src = which ? kr : qr;
    const float* nw = which ? kn : qn;
    bf16* dst = which ? kOut : qOut;
    const int row = blockIdx.x;           // b*S + s
    const int b = row >> 10, s = row & 1023;
    const int t = threadIdx.x;
    __shared__ float xs[D_];
    __shared__ float red[4];

    bf16x8 v = *(const bf16x8*)(src + (size_t)row * D_ + t * 8);
    float x[8]; float ss = 0.f;
#pragma unroll
    for (int j = 0; j < 8; ++j) { x[j] = (float)v[j]; ss += x[j] * x[j]; xs[t * 8 + j] = x[j]; }
#pragma unroll
    for (int msk = 32; msk; msk >>= 1) ss += __shfl_xor(ss, msk, 64);
    if ((t & 63) == 0) red[t >> 6] = ss;
    __syncthreads();
    const float inv = rsqrtf((red[0] + red[1] + red[2] + red[3]) / (float)D_ + EPSF);

    const int h = t >> 4;
    const int dh0 = (t & 15) * 8;
    bf16x8 o;
#pragma unroll
    for (int j = 0; j < 8; ++j) {
        int dd = dh0 + j;
        int d = h * 128 + dd;
        int pd = (dd < 64) ? d + 64 : d - 64;
        float xn = x[j] * inv * nw[d];
        float xp = xs[pd] * inv * nw[pd];
        float rot = (dd < 64) ? -xp : xp;
        o[j] = (bf16)(xn * cosT[s * DH_ + dd] + rot * sinT[s * DH_ + dd]);
    }
    *(bf16x8*)(dst + (((size_t)(b * H_ + h)) * S_ + s) * DH_ + dh0) = o;
}

// ---------------- flash attention (round-7 known-good: Q64, gload_lds, XOR-swizzled LDS) ----------------
__global__ __launch_bounds__(256) void flash(const bf16* __restrict__ Q, const bf16* __restrict__ Kb,
                                             const bf16* __restrict__ VTb, const int* __restrict__ lengths,
                                             bf16* __restrict__ Out) {
    __shared__ bf16 Qs[64 * 128];
    __shared__ bf16 Ks[64 * 128];
    __shared__ bf16 Vt[128 * 64];
    __shared__ bf16 Ps[4][16 * 64];
    const int t = threadIdx.x, w = t >> 6, l = t & 63;
    const int bh = blockIdx.y;
    const int b = bh >> 4;
    const int q0 = blockIdx.x * 64;
    const int L = lengths[b];
    const size_t base = (size_t)bh * S_ * DH_;
    const size_t vbase = (size_t)bh * DH_ * S_;
    const int hi = l >> 4, lo = l & 15;
    const int swz = (lo & 7) << 3;

    {
        const bf16* src = Q + base + (size_t)q0 * DH_;
#pragma unroll
        for (int i = 0; i < 4; ++i) {
            int r = (w * 4 + i) * 4 + (l >> 4);
            int sb = ((l & 15) * 16) ^ ((r & 7) << 4);
            gload_lds16((const void*)(src + (size_t)r * DH_ + (sb >> 1)), (void*)(Qs + (w * 4 + i) * 512));
        }
    }

    f32x4 O[8] = {};
    float mrow[4], lrow[4];
#pragma unroll
    for (int r = 0; r < 4; ++r) { mrow[r] = -1e30f; lrow[r] = 0.f; }
    const int nt = (L + 63) >> 6;
    const float sscale = 0.08838834764831843f;

    for (int kt = 0; kt < nt; ++kt) {
        const int k0 = kt * 64;
        __syncthreads();
        {
            const bf16* ksrc = Kb + base + (size_t)k0 * DH_;
#pragma unroll
            for (int i = 0; i < 4; ++i) {
                int r = (w * 4 + i) * 4 + (l >> 4);
                int sb = ((l & 15) * 16) ^ ((r & 7) << 4);
                gload_lds16((const void*)(ksrc + (size_t)r * DH_ + (sb >> 1)), (void*)(Ks + (w * 4 + i) * 512));
            }
        }
        {
            const bf16* vsrc = VTb + vbase + k0;
#pragma unroll
            for (int i = 0; i < 4; ++i) {
                int d = (w * 4 + i) * 8 + (l >> 3);
                int sb = ((l & 7) * 16) ^ ((d & 7) << 4);
                gload_lds16((const void*)(vsrc + (size_t)d * S_ + (sb >> 1)), (void*)(Vt + (w * 4 + i) * 512));
            }
        }
        __syncthreads();

        f32x4 sc[4] = {};
#pragma unroll
        for (int kk = 0; kk < 4; ++kk) {
            const int ko = kk * 32 + hi * 8;
            bf16x8 aq = *(const bf16x8*)(Qs + (w * 16 + lo) * 128 + (ko ^ swz));
#pragma unroll
            for (int ni = 0; ni < 4; ++ni) {
                bf16x8 bk = *(const bf16x8*)(Ks + (ni * 16 + lo) * 128 + (ko ^ swz));
                sc[ni] = __builtin_amdgcn_mfma_f32_16x16x32_bf16(aq, bk, sc[ni], 0, 0, 0);
            }
        }

        float p[4][4];
#pragma unroll
        for (int r = 0; r < 4; ++r) {
            float sv[4]; float vmax = -1e30f;
#pragma unroll
            for (int ni = 0; ni < 4; ++ni) {
                int kg = k0 + ni * 16 + lo;
                float vv = sc[ni][r] * sscale;
                if (kg >= L) vv = -1e30f;
                sv[ni] = vv;
                vmax = fmaxf(vmax, vv);
            }
#pragma unroll
            for (int msk = 1; msk < 16; msk <<= 1) vmax = fmaxf(vmax, __shfl_xor(vmax, msk, 64));
            float mnew = fmaxf(mrow[r], vmax);
            float corr = __expf(mrow[r] - mnew);
            float rs = 0.f;
#pragma unroll
            for (int ni = 0; ni < 4; ++ni) { float pv = __expf(sv[ni] - mnew); p[r][ni] = pv; rs += pv; }
#pragma unroll
            for (int msk = 1; msk < 16; msk <<= 1) rs += __shfl_xor(rs, msk, 64);
            lrow[r] = lrow[r] * corr + rs;
            mrow[r] = mnew;
#pragma unroll
            for (int di = 0; di < 8; ++di) O[di][r] *= corr;
        }

#pragma unroll
        for (int r = 0; r < 4; ++r) {
            int prow = hi * 4 + r;
#pragma unroll
            for (int ni = 0; ni < 4; ++ni)
                Ps[w][prow * 64 + (((ni * 16 + lo)) ^ ((prow & 7) << 3))] = (bf16)p[r][ni];
        }

#pragma unroll
        for (int kk = 0; kk < 2; ++kk) {
            const int ko = kk * 32 + hi * 8;
            bf16x8 ap = *(const bf16x8*)(&Ps[w][lo * 64 + (ko ^ swz)]);
#pragma unroll
            for (int di = 0; di < 8; ++di) {
                bf16x8 bv = *(const bf16x8*)(Vt + (di * 16 + lo) * 64 + (ko ^ swz));
                O[di] = __builtin_amdgcn_mfma_f32_16x16x32_bf16(ap, bv, O[di], 0, 0, 0);
            }
        }
    }

    const int h = bh & 15;
#pragma unroll
    for (int r = 0; r < 4; ++r) {
        float invl = 1.0f / lrow[r];
        int qrow = q0 + w * 16 + hi * 4 + r;
        bf16* orow = Out + (size_t)(b * S_ + qrow) * D_ + h * DH_;
#pragma unroll
        for (int di = 0; di < 8; ++di)
            orow[di * 16 + lo] = (bf16)(O[di][r] * invl);
    }
}

// ---------------- launch ----------------
extern "C" void kernel_launch(void* const* d_in, const int* in_sizes, int n_in,
                              void* d_out, int out_size, void* d_ws, size_t ws_size,
                              hipStream_t stream) {
    const float* x    = (const float*)d_in[0];
    const float* wq_s = (const float*)d_in[1];
    const float* wk_s = (const float*)d_in[2];
    const float* wv_s = (const float*)d_in[3];
    const float* wo_s = (const float*)d_in[4];
    const float* qn   = (const float*)d_in[5];
    const float* kn   = (const float*)d_in[6];
    const float* cosT = (const float*)d_in[7];
    const float* sinT = (const float*)d_in[8];
    const int* wq = (const int*)d_in[9];
    const int* wk = (const int*)d_in[10];
    const int* wv = (const int*)d_in[11];
    const int* wo = (const int*)d_in[12];
    const int* lengths = (const int*)d_in[13];
    float* out = (float*)d_out;

    char* ws = (char*)d_ws;
    const size_t SLOT = (size_t)M_ * D_ * sizeof(bf16);  // 8 MiB
    bf16* xb   = (bf16*)(ws);
    bf16* wqb  = (bf16*)(ws + 1 * SLOT);   // wqb/wkb/wvb contiguous = Wcat [6144 x 2048]
    bf16* wkb  = (bf16*)(ws + 2 * SLOT);
    bf16* wvb  = (bf16*)(ws + 3 * SLOT);
    bf16* wob  = (bf16*)(ws + 4 * SLOT);
    bf16* qr   = (bf16*)(ws + 5 * SLOT);
    bf16* kr   = (bf16*)(ws + 6 * SLOT);
    bf16* qb2  = (bf16*)(ws + 7 * SLOT);
    bf16* kb2  = (bf16*)(ws + 8 * SLOT);
    bf16* vb2  = (bf16*)(ws + 9 * SLOT);  // V^T layout [B,H,Dh,S]
    bf16* attnb = qr;   // reuse after rope_norm

    const int NW = D_ * D_;  // 4194304
    ConvArgs ca;
    ca.s[0] = x;  ca.d[0] = xb;
    ca.s[1] = wq; ca.d[1] = wqb;
    ca.s[2] = wk; ca.d[2] = wkb;
    ca.s[3] = wv; ca.d[3] = wvb;
    ca.s[4] = wo; ca.d[4] = wob;
    conv_all<<<dim3(NW / 2048, 5), dim3(256), 0, stream>>>(ca, NW);

    QKVArgs qa;
    qa.Sc[0] = wq_s; qa.Sc[1] = wk_s; qa.Sc[2] = wv_s;
    qa.qO = qr; qa.kO = kr; qa.vO = vb2;
    gemmQKV<<<dim3(3 * D_ / 192, M_ / 256), dim3(512), 0, stream>>>(xb, wqb, qa);

    rope_norm<<<dim3(M_, 1, 2), dim3(256), 0, stream>>>(qr, kr, qn, kn, cosT, sinT, qb2, kb2);

    flash<<<dim3(S_ / 64, B_ * H_, 1), dim3(256), 0, stream>>>(qb2, kb2, vb2, lengths, attnb);

    gemmO<<<dim3(D_ / 128, M_ / 128), dim3(256), 0, stream>>>(attnb, wob, wo_s, out);
}

// Round 11
// 145.106 us; speedup vs baseline: 1.1387x; 1.0250x over previous
//
#include <hip/hip_runtime.h>
#include <stdint.h>

typedef __bf16 bf16;
typedef bf16 bf16x8 __attribute__((ext_vector_type(8)));
typedef bf16 bf16x4 __attribute__((ext_vector_type(4)));
typedef float f32x4 __attribute__((ext_vector_type(4)));

#define B_   2
#define S_   1024
#define D_   2048
#define H_   16
#define DH_  128
#define M_   (B_*S_)
#define EPSF 1e-6f

__device__ __forceinline__ void gload_lds16(const void* g, void* l) {
    __builtin_amdgcn_global_load_lds(
        (const __attribute__((address_space(1))) void*)g,
        (__attribute__((address_space(3))) void*)l,
        16, 0, 0);
}

// ---------------- fused conversion kernel (x, wq, wk, wv, wo) ----------------
struct ConvArgs {
    const void* s[5];
    bf16* d[5];
};

__global__ __launch_bounds__(256) void conv_all(ConvArgs a, int n) {
    const int z = blockIdx.y;
    const int i = (blockIdx.x * 256 + threadIdx.x) * 8;
    if (i + 8 > n) return;
    bf16x8 o;
    if (z == 0) {
        const float* src = (const float*)a.s[0];
        float4 v0 = *(const float4*)(src + i);
        float4 v1 = *(const float4*)(src + i + 4);
        o[0] = (bf16)v0.x; o[1] = (bf16)v0.y; o[2] = (bf16)v0.z; o[3] = (bf16)v0.w;
        o[4] = (bf16)v1.x; o[5] = (bf16)v1.y; o[6] = (bf16)v1.z; o[7] = (bf16)v1.w;
    } else {
        const int* src = (const int*)a.s[z];
        int4 v0 = *(const int4*)(src + i);
        int4 v1 = *(const int4*)(src + i + 4);
        o[0] = (bf16)(float)v0.x; o[1] = (bf16)(float)v0.y;
        o[2] = (bf16)(float)v0.z; o[3] = (bf16)(float)v0.w;
        o[4] = (bf16)(float)v1.x; o[5] = (bf16)(float)v1.y;
        o[6] = (bf16)(float)v1.z; o[7] = (bf16)(float)v1.w;
    }
    *(bf16x8*)(a.d[z] + i) = o;
}

// ---------------- QKV GEMM: 128x192 tiles, 8 waves, 2-phase, 2 blocks/CU, 512 blocks full fill ----------------
// C[m,n] = sum_k A[m,k]*Wcat[n,k]*scale; z = n>>11 selects {q,k,v}.
struct QKVArgs {
    const float* Sc[3];
    bf16* qO; bf16* kO; bf16* vO;
};

__global__ __launch_bounds__(512, 4) void gemmQKV(const bf16* __restrict__ A, const bf16* __restrict__ Wcat,
                                                  QKVArgs args) {
    __shared__ char lds[81920];           // 2 x (A 16KB + B 24KB)
    constexpr int NT = D_ / 64;           // 32 K-tiles
    constexpr int BUF = 40960;
    const int t = threadIdx.x;
    const int w = t >> 6, l = t & 63;
    const int wr = w >> 2, wc = w & 3;
    const int m0 = blockIdx.y * 128, n0 = blockIdx.x * 192;
    const int hi = l >> 4, lo = l & 15;

    const int r8 = l >> 3;
    const int ce = ((l & 7) ^ (r8 & 7)) * 8;   // pre-swizzled source column
    const bf16* Ag = A    + (size_t)(m0 + w * 8 + r8) * D_ + ce;
    const bf16* Bg = Wcat + (size_t)(n0 + w * 8 + r8) * D_ + ce;

    auto stage = [&](int kt) {
        if (kt >= NT) return;
        char* d = lds + (kt & 1) * BUF + w * 1024;
        const bf16* ga = Ag + (size_t)kt * 64;
        gload_lds16((const void*)ga, (void*)d);
        gload_lds16((const void*)(ga + (size_t)64 * D_), (void*)(d + 8192));
        const bf16* gb = Bg + (size_t)kt * 64;
        gload_lds16((const void*)gb, (void*)(d + 16384));
        gload_lds16((const void*)(gb + (size_t)64 * D_), (void*)(d + 24576));
        gload_lds16((const void*)(gb + (size_t)128 * D_), (void*)(d + 32768));
    };

    f32x4 acc[4][3] = {};

    stage(0);
    for (int kt = 0; kt < NT; ++kt) {
        const char* cur = lds + (kt & 1) * BUF;
        if (kt + 1 < NT) {
            stage(kt + 1);
            asm volatile("s_waitcnt vmcnt(5)" ::: "memory");
        } else {
            asm volatile("s_waitcnt vmcnt(0)" ::: "memory");
        }
        asm volatile("s_barrier" ::: "memory");

        bf16x8 a[4][2], b[3][2];
#pragma unroll
        for (int mi = 0; mi < 4; ++mi)
#pragma unroll
            for (int kk = 0; kk < 2; ++kk) {
                int row = wr * 64 + mi * 16 + lo;
                a[mi][kk] = *(const bf16x8*)(cur + row * 128 + ((kk * 64 + hi * 16) ^ ((row & 7) << 4)));
            }
#pragma unroll
        for (int ni = 0; ni < 3; ++ni)
#pragma unroll
            for (int kk = 0; kk < 2; ++kk) {
                int row = wc * 48 + ni * 16 + lo;
                b[ni][kk] = *(const bf16x8*)(cur + 16384 + row * 128 + ((kk * 64 + hi * 16) ^ ((row & 7) << 4)));
            }
        __builtin_amdgcn_s_setprio(1);
#pragma unroll
        for (int mi = 0; mi < 4; ++mi)
#pragma unroll
            for (int ni = 0; ni < 3; ++ni)
#pragma unroll
                for (int kk = 0; kk < 2; ++kk)
                    acc[mi][ni] = __builtin_amdgcn_mfma_f32_16x16x32_bf16(a[mi][kk], b[ni][kk], acc[mi][ni], 0, 0, 0);
        __builtin_amdgcn_s_setprio(0);
        asm volatile("s_barrier" ::: "memory");
    }

    // epilogue: n -> z = n>>11 (0:q, 1:k, 2:v)
#pragma unroll
    for (int ni = 0; ni < 3; ++ni) {
        const int n = n0 + wc * 48 + ni * 16 + lo;
        const int z = n >> 11, col = n & 2047;
        const float scv = args.Sc[z][col];
#pragma unroll
        for (int mi = 0; mi < 4; ++mi) {
            const int mb = m0 + wr * 64 + mi * 16 + hi * 4;
            if (z == 2) {
                bf16x4 pk;
#pragma unroll
                for (int r = 0; r < 4; ++r) pk[r] = (bf16)(acc[mi][ni][r] * scv);
                const int bb = mb >> 10, s = mb & 1023, hh = col >> 7, dh = col & 127;
                *(bf16x4*)(args.vO + (((size_t)(bb * H_ + hh)) * DH_ + dh) * S_ + s) = pk;
            } else {
                bf16* dst = (z == 0 ? args.qO : args.kO);
#pragma unroll
                for (int r = 0; r < 4; ++r)
                    dst[(size_t)(mb + r) * D_ + col] = (bf16)(acc[mi][ni][r] * scv);
            }
        }
    }
}

// ---------------- O-proj GEMM: BM=BN=128, 4 waves, 2-phase counted vmcnt ----------------
__global__ __launch_bounds__(256, 2) void gemmO(const bf16* __restrict__ A, const bf16* __restrict__ W,
                                                const float* __restrict__ Sc, float* __restrict__ O) {
    __shared__ char lds[65536];
    constexpr int NT = D_ / 64;
    const int t = threadIdx.x;
    const int w = t >> 6, l = t & 63;
    const int wr = w >> 1, wc = w & 1;
    const int m0 = blockIdx.y * 128, n0 = blockIdx.x * 128;
    const int hi = l >> 4, lo = l & 15;

    const int r8 = l >> 3;
    const int ce = ((l & 7) ^ (r8 & 7)) * 8;
    const bf16* Ag = A + (size_t)(m0 + w * 8 + r8) * D_ + ce;
    const bf16* Bg = W + (size_t)(n0 + w * 8 + r8) * D_ + ce;

    auto stage = [&](int kt) {
        char* d = lds + (kt & 1) * 32768 + w * 1024;
        const bf16* ga = Ag + (size_t)kt * 64;
        const bf16* gb = Bg + (size_t)kt * 64;
#pragma unroll
        for (int j = 0; j < 4; ++j) {
            gload_lds16((const void*)(ga + (size_t)j * 32 * D_), (void*)(d + j * 4096));
            gload_lds16((const void*)(gb + (size_t)j * 32 * D_), (void*)(d + 16384 + j * 4096));
        }
    };

    f32x4 acc[4][4] = {};
    stage(0);
    for (int kt = 0; kt < NT; ++kt) {
        const char* cur = lds + (kt & 1) * 32768;
        if (kt + 1 < NT) {
            stage(kt + 1);
            asm volatile("s_waitcnt vmcnt(8)" ::: "memory");
        } else {
            asm volatile("s_waitcnt vmcnt(0)" ::: "memory");
        }
        asm volatile("s_barrier" ::: "memory");

        bf16x8 a[4][2], b[4][2];
#pragma unroll
        for (int mi = 0; mi < 4; ++mi)
#pragma unroll
            for (int kk = 0; kk < 2; ++kk) {
                int row = wr * 64 + mi * 16 + lo;
                a[mi][kk] = *(const bf16x8*)(cur + row * 128 + ((kk * 64 + hi * 16) ^ ((row & 7) << 4)));
            }
#pragma unroll
        for (int ni = 0; ni < 4; ++ni)
#pragma unroll
            for (int kk = 0; kk < 2; ++kk) {
                int row = wc * 64 + ni * 16 + lo;
                b[ni][kk] = *(const bf16x8*)(cur + 16384 + row * 128 + ((kk * 64 + hi * 16) ^ ((row & 7) << 4)));
            }
        __builtin_amdgcn_s_setprio(1);
#pragma unroll
        for (int mi = 0; mi < 4; ++mi)
#pragma unroll
            for (int ni = 0; ni < 4; ++ni)
#pragma unroll
                for (int kk = 0; kk < 2; ++kk)
                    acc[mi][ni] = __builtin_amdgcn_mfma_f32_16x16x32_bf16(a[mi][kk], b[ni][kk], acc[mi][ni], 0, 0, 0);
        __builtin_amdgcn_s_setprio(0);
        asm volatile("s_barrier" ::: "memory");
    }

#pragma unroll
    for (int ni = 0; ni < 4; ++ni) {
        const int n = n0 + wc * 64 + ni * 16 + lo;
        const float scv = Sc[n];
#pragma unroll
        for (int mi = 0; mi < 4; ++mi) {
            const int mb = m0 + wr * 64 + mi * 16 + hi * 4;
#pragma unroll
            for (int r = 0; r < 4; ++r)
                O[(size_t)(mb + r) * D_ + n] = acc[mi][ni][r] * scv;
        }
    }
}

// ---------------- RMSNorm + RoPE + transpose to [B,H,S,Dh] (round-7 known-good) ----------------
__global__ __launch_bounds__(256) void rope_norm(const bf16* __restrict__ qr, const bf16* __restrict__ kr,
                                                 const float* __restrict__ qn, const float* __restrict__ kn,
                                                 const float* __restrict__ cosT, const float* __restrict__ sinT,
                                                 bf16* __restrict__ qOut, bf16* __restrict__ kOut) {
    const int which = blockIdx.z;
    const bf16* src = which ? kr : qr;
    const float* nw = which ? kn : qn;
    bf16* dst = which ? kOut : qOut;
    const int row = blockIdx.x;           // b*S + s
    const int b = row >> 10, s = row & 1023;
    const int t = threadIdx.x;
    __shared__ float xs[D_];
    __shared__ float red[4];

    bf16x8 v = *(const bf16x8*)(src + (size_t)row * D_ + t * 8);
    float x[8]; float ss = 0.f;
#pragma unroll
    for (int j = 0; j < 8; ++j) { x[j] = (float)v[j]; ss += x[j] * x[j]; xs[t * 8 + j] = x[j]; }
#pragma unroll
    for (int msk = 32; msk; msk >>= 1) ss += __shfl_xor(ss, msk, 64);
    if ((t & 63) == 0) red[t >> 6] = ss;
    __syncthreads();
    const float inv = rsqrtf((red[0] + red[1] + red[2] + red[3]) / (float)D_ + EPSF);

    const int h = t >> 4;
    const int dh0 = (t & 15) * 8;
    bf16x8 o;
#pragma unroll
    for (int j = 0; j < 8; ++j) {
        int dd = dh0 + j;
        int d = h * 128 + dd;
        int pd = (dd < 64) ? d + 64 : d - 64;
        float xn = x[j] * inv * nw[d];
        float xp = xs[pd] * inv * nw[pd];
        float rot = (dd < 64) ? -xp : xp;
        o[j] = (bf16)(xn * cosT[s * DH_ + dd] + rot * sinT[s * DH_ + dd]);
    }
    *(bf16x8*)(dst + (((size_t)(b * H_ + h)) * S_ + s) * DH_ + dh0) = o;
}

// ---------------- flash attention (round-7 known-good: Q64, gload_lds, XOR-swizzled LDS) ----------------
__global__ __launch_bounds__(256) void flash(const bf16* __restrict__ Q, const bf16* __restrict__ Kb,
                                             const bf16* __restrict__ VTb, const int* __restrict__ lengths,
                                             bf16* __restrict__ Out) {
    __shared__ bf16 Qs[64 * 128];
    __shared__ bf16 Ks[64 * 128];
    __shared__ bf16 Vt[128 * 64];
    __shared__ bf16 Ps[4][16 * 64];
    const int t = threadIdx.x, w = t >> 6, l = t & 63;
    const int bh = blockIdx.y;
    const int b = bh >> 4;
    const int q0 = blockIdx.x * 64;
    const int L = lengths[b];
    const size_t base = (size_t)bh * S_ * DH_;
    const size_t vbase = (size_t)bh * DH_ * S_;
    const int hi = l >> 4, lo = l & 15;
    const int swz = (lo & 7) << 3;

    {
        const bf16* src = Q + base + (size_t)q0 * DH_;
#pragma unroll
        for (int i = 0; i < 4; ++i) {
            int r = (w * 4 + i) * 4 + (l >> 4);
            int sb = ((l & 15) * 16) ^ ((r & 7) << 4);
            gload_lds16((const void*)(src + (size_t)r * DH_ + (sb >> 1)), (void*)(Qs + (w * 4 + i) * 512));
        }
    }

    f32x4 O[8] = {};
    float mrow[4], lrow[4];
#pragma unroll
    for (int r = 0; r < 4; ++r) { mrow[r] = -1e30f; lrow[r] = 0.f; }
    const int nt = (L + 63) >> 6;
    const float sscale = 0.08838834764831843f;

    for (int kt = 0; kt < nt; ++kt) {
        const int k0 = kt * 64;
        __syncthreads();
        {
            const bf16* ksrc = Kb + base + (size_t)k0 * DH_;
#pragma unroll
            for (int i = 0; i < 4; ++i) {
                int r = (w * 4 + i) * 4 + (l >> 4);
                int sb = ((l & 15) * 16) ^ ((r & 7) << 4);
                gload_lds16((const void*)(ksrc + (size_t)r * DH_ + (sb >> 1)), (void*)(Ks + (w * 4 + i) * 512));
            }
        }
        {
            const bf16* vsrc = VTb + vbase + k0;
#pragma unroll
            for (int i = 0; i < 4; ++i) {
                int d = (w * 4 + i) * 8 + (l >> 3);
                int sb = ((l & 7) * 16) ^ ((d & 7) << 4);
                gload_lds16((const void*)(vsrc + (size_t)d * S_ + (sb >> 1)), (void*)(Vt + (w * 4 + i) * 512));
            }
        }
        __syncthreads();

        f32x4 sc[4] = {};
#pragma unroll
        for (int kk = 0; kk < 4; ++kk) {
            const int ko = kk * 32 + hi * 8;
            bf16x8 aq = *(const bf16x8*)(Qs + (w * 16 + lo) * 128 + (ko ^ swz));
#pragma unroll
            for (int ni = 0; ni < 4; ++ni) {
                bf16x8 bk = *(const bf16x8*)(Ks + (ni * 16 + lo) * 128 + (ko ^ swz));
                sc[ni] = __builtin_amdgcn_mfma_f32_16x16x32_bf16(aq, bk, sc[ni], 0, 0, 0);
            }
        }

        float p[4][4];
#pragma unroll
        for (int r = 0; r < 4; ++r) {
            float sv[4]; float vmax = -1e30f;
#pragma unroll
            for (int ni = 0; ni < 4; ++ni) {
                int kg = k0 + ni * 16 + lo;
                float vv = sc[ni][r] * sscale;
                if (kg >= L) vv = -1e30f;
                sv[ni] = vv;
                vmax = fmaxf(vmax, vv);
            }
#pragma unroll
            for (int msk = 1; msk < 16; msk <<= 1) vmax = fmaxf(vmax, __shfl_xor(vmax, msk, 64));
            float mnew = fmaxf(mrow[r], vmax);
            float corr = __expf(mrow[r] - mnew);
            float rs = 0.f;
#pragma unroll
            for (int ni = 0; ni < 4; ++ni) { float pv = __expf(sv[ni] - mnew); p[r][ni] = pv; rs += pv; }
#pragma unroll
            for (int msk = 1; msk < 16; msk <<= 1) rs += __shfl_xor(rs, msk, 64);
            lrow[r] = lrow[r] * corr + rs;
            mrow[r] = mnew;
#pragma unroll
            for (int di = 0; di < 8; ++di) O[di][r] *= corr;
        }

#pragma unroll
        for (int r = 0; r < 4; ++r) {
            int prow = hi * 4 + r;
#pragma unroll
            for (int ni = 0; ni < 4; ++ni)
                Ps[w][prow * 64 + (((ni * 16 + lo)) ^ ((prow & 7) << 3))] = (bf16)p[r][ni];
        }

#pragma unroll
        for (int kk = 0; kk < 2; ++kk) {
            const int ko = kk * 32 + hi * 8;
            bf16x8 ap = *(const bf16x8*)(&Ps[w][lo * 64 + (ko ^ swz)]);
#pragma unroll
            for (int di = 0; di < 8; ++di) {
                bf16x8 bv = *(const bf16x8*)(Vt + (di * 16 + lo) * 64 + (ko ^ swz));
                O[di] = __builtin_amdgcn_mfma_f32_16x16x32_bf16(ap, bv, O[di], 0, 0, 0);
            }
        }
    }

    const int h = bh & 15;
#pragma unroll
    for (int r = 0; r < 4; ++r) {
        float invl = 1.0f / lrow[r];
        int qrow = q0 + w * 16 + hi * 4 + r;
        bf16* orow = Out + (size_t)(b * S_ + qrow) * D_ + h * DH_;
#pragma unroll
        for (int di = 0; di < 8; ++di)
            orow[di * 16 + lo] = (bf16)(O[di][r] * invl);
    }
}

// ---------------- launch ----------------
extern "C" void kernel_launch(void* const* d_in, const int* in_sizes, int n_in,
                              void* d_out, int out_size, void* d_ws, size_t ws_size,
                              hipStream_t stream) {
    const float* x    = (const float*)d_in[0];
    const float* wq_s = (const float*)d_in[1];
    const float* wk_s = (const float*)d_in[2];
    const float* wv_s = (const float*)d_in[3];
    const float* wo_s = (const float*)d_in[4];
    const float* qn   = (const float*)d_in[5];
    const float* kn   = (const float*)d_in[6];
    const float* cosT = (const float*)d_in[7];
    const float* sinT = (const float*)d_in[8];
    const int* wq = (const int*)d_in[9];
    const int* wk = (const int*)d_in[10];
    const int* wv = (const int*)d_in[11];
    const int* wo = (const int*)d_in[12];
    const int* lengths = (const int*)d_in[13];
    float* out = (float*)d_out;

    char* ws = (char*)d_ws;
    const size_t SLOT = (size_t)M_ * D_ * sizeof(bf16);  // 8 MiB
    bf16* xb   = (bf16*)(ws);
    bf16* wqb  = (bf16*)(ws + 1 * SLOT);   // wqb/wkb/wvb contiguous = Wcat [6144 x 2048]
    bf16* wkb  = (bf16*)(ws + 2 * SLOT);
    bf16* wvb  = (bf16*)(ws + 3 * SLOT);
    bf16* wob  = (bf16*)(ws + 4 * SLOT);
    bf16* qr   = (bf16*)(ws + 5 * SLOT);
    bf16* kr   = (bf16*)(ws + 6 * SLOT);
    bf16* qb2  = (bf16*)(ws + 7 * SLOT);
    bf16* kb2  = (bf16*)(ws + 8 * SLOT);
    bf16* vb2  = (bf16*)(ws + 9 * SLOT);  // V^T layout [B,H,Dh,S]
    bf16* attnb = qr;   // reuse after rope_norm

    const int NW = D_ * D_;  // 4194304
    ConvArgs ca;
    ca.s[0] = x;  ca.d[0] = xb;
    ca.s[1] = wq; ca.d[1] = wqb;
    ca.s[2] = wk; ca.d[2] = wkb;
    ca.s[3] = wv; ca.d[3] = wvb;
    ca.s[4] = wo; ca.d[4] = wob;
    conv_all<<<dim3(NW / 2048, 5), dim3(256), 0, stream>>>(ca, NW);

    QKVArgs qa;
    qa.Sc[0] = wq_s; qa.Sc[1] = wk_s; qa.Sc[2] = wv_s;
    qa.qO = qr; qa.kO = kr; qa.vO = vb2;
    gemmQKV<<<dim3(3 * D_ / 192, M_ / 128), dim3(512), 0, stream>>>(xb, wqb, qa);

    rope_norm<<<dim3(M_, 1, 2), dim3(256), 0, stream>>>(qr, kr, qn, kn, cosT, sinT, qb2, kb2);

    flash<<<dim3(S_ / 64, B_ * H_, 1), dim3(256), 0, stream>>>(qb2, kb2, vb2, lengths, attnb);

    gemmO<<<dim3(D_ / 128, M_ / 128), dim3(256), 0, stream>>>(attnb, wob, wo_s, out);
}

// Round 12
// 144.193 us; speedup vs baseline: 1.1459x; 1.0063x over previous
//
#include <hip/hip_runtime.h>
#include <stdint.h>

typedef __bf16 bf16;
typedef bf16 bf16x8 __attribute__((ext_vector_type(8)));
typedef bf16 bf16x4 __attribute__((ext_vector_type(4)));
typedef float f32x4 __attribute__((ext_vector_type(4)));

#define B_   2
#define S_   1024
#define D_   2048
#define H_   16
#define DH_  128
#define M_   (B_*S_)
#define EPSF 1e-6f

__device__ __forceinline__ void gload_lds16(const void* g, void* l) {
    __builtin_amdgcn_global_load_lds(
        (const __attribute__((address_space(1))) void*)g,
        (__attribute__((address_space(3))) void*)l,
        16, 0, 0);
}

// ---------------- fused conversion kernel (x, wq, wk, wv, wo) ----------------
struct ConvArgs {
    const void* s[5];
    bf16* d[5];
};

__global__ __launch_bounds__(256) void conv_all(ConvArgs a, int n) {
    const int z = blockIdx.y;
    const int i = (blockIdx.x * 256 + threadIdx.x) * 8;
    if (i + 8 > n) return;
    bf16x8 o;
    if (z == 0) {
        const float* src = (const float*)a.s[0];
        float4 v0 = *(const float4*)(src + i);
        float4 v1 = *(const float4*)(src + i + 4);
        o[0] = (bf16)v0.x; o[1] = (bf16)v0.y; o[2] = (bf16)v0.z; o[3] = (bf16)v0.w;
        o[4] = (bf16)v1.x; o[5] = (bf16)v1.y; o[6] = (bf16)v1.z; o[7] = (bf16)v1.w;
    } else {
        const int* src = (const int*)a.s[z];
        int4 v0 = *(const int4*)(src + i);
        int4 v1 = *(const int4*)(src + i + 4);
        o[0] = (bf16)(float)v0.x; o[1] = (bf16)(float)v0.y;
        o[2] = (bf16)(float)v0.z; o[3] = (bf16)(float)v0.w;
        o[4] = (bf16)(float)v1.x; o[5] = (bf16)(float)v1.y;
        o[6] = (bf16)(float)v1.z; o[7] = (bf16)(float)v1.w;
    }
    *(bf16x8*)(a.d[z] + i) = o;
}

// ---------------- QKV GEMM: 128x192 tiles, 8 waves, 2-phase, 2 blocks/CU, 512 blocks full fill ----------------
struct QKVArgs {
    const float* Sc[3];
    bf16* qO; bf16* kO; bf16* vO;
};

__global__ __launch_bounds__(512, 4) void gemmQKV(const bf16* __restrict__ A, const bf16* __restrict__ Wcat,
                                                  QKVArgs args) {
    __shared__ char lds[81920];           // 2 x (A 16KB + B 24KB)
    constexpr int NT = D_ / 64;           // 32 K-tiles
    constexpr int BUF = 40960;
    const int t = threadIdx.x;
    const int w = t >> 6, l = t & 63;
    const int wr = w >> 2, wc = w & 3;
    const int m0 = blockIdx.y * 128, n0 = blockIdx.x * 192;
    const int hi = l >> 4, lo = l & 15;

    const int r8 = l >> 3;
    const int ce = ((l & 7) ^ (r8 & 7)) * 8;   // pre-swizzled source column
    const bf16* Ag = A    + (size_t)(m0 + w * 8 + r8) * D_ + ce;
    const bf16* Bg = Wcat + (size_t)(n0 + w * 8 + r8) * D_ + ce;

    auto stage = [&](int kt) {
        if (kt >= NT) return;
        char* d = lds + (kt & 1) * BUF + w * 1024;
        const bf16* ga = Ag + (size_t)kt * 64;
        gload_lds16((const void*)ga, (void*)d);
        gload_lds16((const void*)(ga + (size_t)64 * D_), (void*)(d + 8192));
        const bf16* gb = Bg + (size_t)kt * 64;
        gload_lds16((const void*)gb, (void*)(d + 16384));
        gload_lds16((const void*)(gb + (size_t)64 * D_), (void*)(d + 24576));
        gload_lds16((const void*)(gb + (size_t)128 * D_), (void*)(d + 32768));
    };

    f32x4 acc[4][3] = {};

    stage(0);
    for (int kt = 0; kt < NT; ++kt) {
        const char* cur = lds + (kt & 1) * BUF;
        if (kt + 1 < NT) {
            stage(kt + 1);
            asm volatile("s_waitcnt vmcnt(5)" ::: "memory");
        } else {
            asm volatile("s_waitcnt vmcnt(0)" ::: "memory");
        }
        asm volatile("s_barrier" ::: "memory");

        bf16x8 a[4][2], b[3][2];
#pragma unroll
        for (int mi = 0; mi < 4; ++mi)
#pragma unroll
            for (int kk = 0; kk < 2; ++kk) {
                int row = wr * 64 + mi * 16 + lo;
                a[mi][kk] = *(const bf16x8*)(cur + row * 128 + ((kk * 64 + hi * 16) ^ ((row & 7) << 4)));
            }
#pragma unroll
        for (int ni = 0; ni < 3; ++ni)
#pragma unroll
            for (int kk = 0; kk < 2; ++kk) {
                int row = wc * 48 + ni * 16 + lo;
                b[ni][kk] = *(const bf16x8*)(cur + 16384 + row * 128 + ((kk * 64 + hi * 16) ^ ((row & 7) << 4)));
            }
        __builtin_amdgcn_s_setprio(1);
#pragma unroll
        for (int mi = 0; mi < 4; ++mi)
#pragma unroll
            for (int ni = 0; ni < 3; ++ni)
#pragma unroll
                for (int kk = 0; kk < 2; ++kk)
                    acc[mi][ni] = __builtin_amdgcn_mfma_f32_16x16x32_bf16(a[mi][kk], b[ni][kk], acc[mi][ni], 0, 0, 0);
        __builtin_amdgcn_s_setprio(0);
        asm volatile("s_barrier" ::: "memory");
    }

    // epilogue: n -> z = n>>11 (0:q, 1:k, 2:v)
#pragma unroll
    for (int ni = 0; ni < 3; ++ni) {
        const int n = n0 + wc * 48 + ni * 16 + lo;
        const int z = n >> 11, col = n & 2047;
        const float scv = args.Sc[z][col];
#pragma unroll
        for (int mi = 0; mi < 4; ++mi) {
            const int mb = m0 + wr * 64 + mi * 16 + hi * 4;
            if (z == 2) {
                bf16x4 pk;
#pragma unroll
                for (int r = 0; r < 4; ++r) pk[r] = (bf16)(acc[mi][ni][r] * scv);
                const int bb = mb >> 10, s = mb & 1023, hh = col >> 7, dh = col & 127;
                *(bf16x4*)(args.vO + (((size_t)(bb * H_ + hh)) * DH_ + dh) * S_ + s) = pk;
            } else {
                bf16* dst = (z == 0 ? args.qO : args.kO);
#pragma unroll
                for (int r = 0; r < 4; ++r)
                    dst[(size_t)(mb + r) * D_ + col] = (bf16)(acc[mi][ni][r] * scv);
            }
        }
    }
}

// ---------------- O-proj GEMM: BM=BN=128, 4 waves, 2-phase counted vmcnt ----------------
__global__ __launch_bounds__(256, 2) void gemmO(const bf16* __restrict__ A, const bf16* __restrict__ W,
                                                const float* __restrict__ Sc, float* __restrict__ O) {
    __shared__ char lds[65536];
    constexpr int NT = D_ / 64;
    const int t = threadIdx.x;
    const int w = t >> 6, l = t & 63;
    const int wr = w >> 1, wc = w & 1;
    const int m0 = blockIdx.y * 128, n0 = blockIdx.x * 128;
    const int hi = l >> 4, lo = l & 15;

    const int r8 = l >> 3;
    const int ce = ((l & 7) ^ (r8 & 7)) * 8;
    const bf16* Ag = A + (size_t)(m0 + w * 8 + r8) * D_ + ce;
    const bf16* Bg = W + (size_t)(n0 + w * 8 + r8) * D_ + ce;

    auto stage = [&](int kt) {
        char* d = lds + (kt & 1) * 32768 + w * 1024;
        const bf16* ga = Ag + (size_t)kt * 64;
        const bf16* gb = Bg + (size_t)kt * 64;
#pragma unroll
        for (int j = 0; j < 4; ++j) {
            gload_lds16((const void*)(ga + (size_t)j * 32 * D_), (void*)(d + j * 4096));
            gload_lds16((const void*)(gb + (size_t)j * 32 * D_), (void*)(d + 16384 + j * 4096));
        }
    };

    f32x4 acc[4][4] = {};
    stage(0);
    for (int kt = 0; kt < NT; ++kt) {
        const char* cur = lds + (kt & 1) * 32768;
        if (kt + 1 < NT) {
            stage(kt + 1);
            asm volatile("s_waitcnt vmcnt(8)" ::: "memory");
        } else {
            asm volatile("s_waitcnt vmcnt(0)" ::: "memory");
        }
        asm volatile("s_barrier" ::: "memory");

        bf16x8 a[4][2], b[4][2];
#pragma unroll
        for (int mi = 0; mi < 4; ++mi)
#pragma unroll
            for (int kk = 0; kk < 2; ++kk) {
                int row = wr * 64 + mi * 16 + lo;
                a[mi][kk] = *(const bf16x8*)(cur + row * 128 + ((kk * 64 + hi * 16) ^ ((row & 7) << 4)));
            }
#pragma unroll
        for (int ni = 0; ni < 4; ++ni)
#pragma unroll
            for (int kk = 0; kk < 2; ++kk) {
                int row = wc * 64 + ni * 16 + lo;
                b[ni][kk] = *(const bf16x8*)(cur + 16384 + row * 128 + ((kk * 64 + hi * 16) ^ ((row & 7) << 4)));
            }
        __builtin_amdgcn_s_setprio(1);
#pragma unroll
        for (int mi = 0; mi < 4; ++mi)
#pragma unroll
            for (int ni = 0; ni < 4; ++ni)
#pragma unroll
                for (int kk = 0; kk < 2; ++kk)
                    acc[mi][ni] = __builtin_amdgcn_mfma_f32_16x16x32_bf16(a[mi][kk], b[ni][kk], acc[mi][ni], 0, 0, 0);
        __builtin_amdgcn_s_setprio(0);
        asm volatile("s_barrier" ::: "memory");
    }

#pragma unroll
    for (int ni = 0; ni < 4; ++ni) {
        const int n = n0 + wc * 64 + ni * 16 + lo;
        const float scv = Sc[n];
#pragma unroll
        for (int mi = 0; mi < 4; ++mi) {
            const int mb = m0 + wr * 64 + mi * 16 + hi * 4;
#pragma unroll
            for (int r = 0; r < 4; ++r)
                O[(size_t)(mb + r) * D_ + n] = acc[mi][ni][r] * scv;
        }
    }
}

// ---------------- RMSNorm + RoPE, shuffle-based rotate-half (no xs LDS), transpose to [B,H,S,Dh] ----------------
// partner of element dh is dh^64 -> lane l^8 within the same wave (dh0 = (t&15)*8)
__global__ __launch_bounds__(256) void rope_norm(const bf16* __restrict__ qr, const bf16* __restrict__ kr,
                                                 const float* __restrict__ qn, const float* __restrict__ kn,
                                                 const float* __restrict__ cosT, const float* __restrict__ sinT,
                                                 bf16* __restrict__ qOut, bf16* __restrict__ kOut) {
    const int which = blockIdx.z;
    const bf16* src = which ? kr : qr;
    const float* nw = which ? kn : qn;
    bf16* dst = which ? kOut : qOut;
    const int row = blockIdx.x;           // b*S + s
    const int b = row >> 10, s = row & 1023;
    const int t = threadIdx.x;
    __shared__ float red[4];

    bf16x8 v = *(const bf16x8*)(src + (size_t)row * D_ + t * 8);
    float x[8]; float ss = 0.f;
#pragma unroll
    for (int j = 0; j < 8; ++j) { x[j] = (float)v[j]; ss += x[j] * x[j]; }
#pragma unroll
    for (int msk = 32; msk; msk >>= 1) ss += __shfl_xor(ss, msk, 64);
    if ((t & 63) == 0) red[t >> 6] = ss;
    __syncthreads();
    const float inv = rsqrtf((red[0] + red[1] + red[2] + red[3]) / (float)D_ + EPSF);

    const int h = t >> 4;
    const int dh0 = (t & 15) * 8;
    float xn[8];
#pragma unroll
    for (int j = 0; j < 8; ++j) xn[j] = x[j] * inv * nw[h * 128 + dh0 + j];

    bf16x8 o;
#pragma unroll
    for (int j = 0; j < 8; ++j) {
        float xp = __shfl_xor(xn[j], 8, 64);         // partner's normalized value (dh^64)
        float rot = (dh0 < 64) ? -xp : xp;
        o[j] = (bf16)(xn[j] * cosT[s * DH_ + dh0 + j] + rot * sinT[s * DH_ + dh0 + j]);
    }
    *(bf16x8*)(dst + (((size_t)(b * H_ + h)) * S_ + s) * DH_ + dh0) = o;
}

// ---------------- flash attention (round-7 known-good: Q64, gload_lds, XOR-swizzled LDS) ----------------
__global__ __launch_bounds__(256) void flash(const bf16* __restrict__ Q, const bf16* __restrict__ Kb,
                                             const bf16* __restrict__ VTb, const int* __restrict__ lengths,
                                             bf16* __restrict__ Out) {
    __shared__ bf16 Qs[64 * 128];
    __shared__ bf16 Ks[64 * 128];
    __shared__ bf16 Vt[128 * 64];
    __shared__ bf16 Ps[4][16 * 64];
    const int t = threadIdx.x, w = t >> 6, l = t & 63;
    const int bh = blockIdx.y;
    const int b = bh >> 4;
    const int q0 = blockIdx.x * 64;
    const int L = lengths[b];
    const size_t base = (size_t)bh * S_ * DH_;
    const size_t vbase = (size_t)bh * DH_ * S_;
    const int hi = l >> 4, lo = l & 15;
    const int swz = (lo & 7) << 3;

    {
        const bf16* src = Q + base + (size_t)q0 * DH_;
#pragma unroll
        for (int i = 0; i < 4; ++i) {
            int r = (w * 4 + i) * 4 + (l >> 4);
            int sb = ((l & 15) * 16) ^ ((r & 7) << 4);
            gload_lds16((const void*)(src + (size_t)r * DH_ + (sb >> 1)), (void*)(Qs + (w * 4 + i) * 512));
        }
    }

    f32x4 O[8] = {};
    float mrow[4], lrow[4];
#pragma unroll
    for (int r = 0; r < 4; ++r) { mrow[r] = -1e30f; lrow[r] = 0.f; }
    const int nt = (L + 63) >> 6;
    const float sscale = 0.08838834764831843f;

    for (int kt = 0; kt < nt; ++kt) {
        const int k0 = kt * 64;
        __syncthreads();
        {
            const bf16* ksrc = Kb + base + (size_t)k0 * DH_;
#pragma unroll
            for (int i = 0; i < 4; ++i) {
                int r = (w * 4 + i) * 4 + (l >> 4);
                int sb = ((l & 15) * 16) ^ ((r & 7) << 4);
                gload_lds16((const void*)(ksrc + (size_t)r * DH_ + (sb >> 1)), (void*)(Ks + (w * 4 + i) * 512));
            }
        }
        {
            const bf16* vsrc = VTb + vbase + k0;
#pragma unroll
            for (int i = 0; i < 4; ++i) {
                int d = (w * 4 + i) * 8 + (l >> 3);
                int sb = ((l & 7) * 16) ^ ((d & 7) << 4);
                gload_lds16((const void*)(vsrc + (size_t)d * S_ + (sb >> 1)), (void*)(Vt + (w * 4 + i) * 512));
            }
        }
        __syncthreads();

        f32x4 sc[4] = {};
#pragma unroll
        for (int kk = 0; kk < 4; ++kk) {
            const int ko = kk * 32 + hi * 8;
            bf16x8 aq = *(const bf16x8*)(Qs + (w * 16 + lo) * 128 + (ko ^ swz));
#pragma unroll
            for (int ni = 0; ni < 4; ++ni) {
                bf16x8 bk = *(const bf16x8*)(Ks + (ni * 16 + lo) * 128 + (ko ^ swz));
                sc[ni] = __builtin_amdgcn_mfma_f32_16x16x32_bf16(aq, bk, sc[ni], 0, 0, 0);
            }
        }

        float p[4][4];
#pragma unroll
        for (int r = 0; r < 4; ++r) {
            float sv[4]; float vmax = -1e30f;
#pragma unroll
            for (int ni = 0; ni < 4; ++ni) {
                int kg = k0 + ni * 16 + lo;
                float vv = sc[ni][r] * sscale;
                if (kg >= L) vv = -1e30f;
                sv[ni] = vv;
                vmax = fmaxf(vmax, vv);
            }
#pragma unroll
            for (int msk = 1; msk < 16; msk <<= 1) vmax = fmaxf(vmax, __shfl_xor(vmax, msk, 64));
            float mnew = fmaxf(mrow[r], vmax);
            float corr = __expf(mrow[r] - mnew);
            float rs = 0.f;
#pragma unroll
            for (int ni = 0; ni < 4; ++ni) { float pv = __expf(sv[ni] - mnew); p[r][ni] = pv; rs += pv; }
#pragma unroll
            for (int msk = 1; msk < 16; msk <<= 1) rs += __shfl_xor(rs, msk, 64);
            lrow[r] = lrow[r] * corr + rs;
            mrow[r] = mnew;
#pragma unroll
            for (int di = 0; di < 8; ++di) O[di][r] *= corr;
        }

#pragma unroll
        for (int r = 0; r < 4; ++r) {
            int prow = hi * 4 + r;
#pragma unroll
            for (int ni = 0; ni < 4; ++ni)
                Ps[w][prow * 64 + (((ni * 16 + lo)) ^ ((prow & 7) << 3))] = (bf16)p[r][ni];
        }

#pragma unroll
        for (int kk = 0; kk < 2; ++kk) {
            const int ko = kk * 32 + hi * 8;
            bf16x8 ap = *(const bf16x8*)(&Ps[w][lo * 64 + (ko ^ swz)]);
#pragma unroll
            for (int di = 0; di < 8; ++di) {
                bf16x8 bv = *(const bf16x8*)(Vt + (di * 16 + lo) * 64 + (ko ^ swz));
                O[di] = __builtin_amdgcn_mfma_f32_16x16x32_bf16(ap, bv, O[di], 0, 0, 0);
            }
        }
    }

    const int h = bh & 15;
#pragma unroll
    for (int r = 0; r < 4; ++r) {
        float invl = 1.0f / lrow[r];
        int qrow = q0 + w * 16 + hi * 4 + r;
        bf16* orow = Out + (size_t)(b * S_ + qrow) * D_ + h * DH_;
#pragma unroll
        for (int di = 0; di < 8; ++di)
            orow[di * 16 + lo] = (bf16)(O[di][r] * invl);
    }
}

// ---------------- launch ----------------
extern "C" void kernel_launch(void* const* d_in, const int* in_sizes, int n_in,
                              void* d_out, int out_size, void* d_ws, size_t ws_size,
                              hipStream_t stream) {
    const float* x    = (const float*)d_in[0];
    const float* wq_s = (const float*)d_in[1];
    const float* wk_s = (const float*)d_in[2];
    const float* wv_s = (const float*)d_in[3];
    const float* wo_s = (const float*)d_in[4];
    const float* qn   = (const float*)d_in[5];
    const float* kn   = (const float*)d_in[6];
    const float* cosT = (const float*)d_in[7];
    const float* sinT = (const float*)d_in[8];
    const int* wq = (const int*)d_in[9];
    const int* wk = (const int*)d_in[10];
    const int* wv = (const int*)d_in[11];
    const int* wo = (const int*)d_in[12];
    const int* lengths = (const int*)d_in[13];
    float* out = (float*)d_out;

    char* ws = (char*)d_ws;
    const size_t SLOT = (size_t)M_ * D_ * sizeof(bf16);  // 8 MiB
    bf16* xb   = (bf16*)(ws);
    bf16* wqb  = (bf16*)(ws + 1 * SLOT);   // wqb/wkb/wvb contiguous = Wcat [6144 x 2048]
    bf16* wkb  = (bf16*)(ws + 2 * SLOT);
    bf16* wvb  = (bf16*)(ws + 3 * SLOT);
    bf16* wob  = (bf16*)(ws + 4 * SLOT);
    bf16* qr   = (bf16*)(ws + 5 * SLOT);
    bf16* kr   = (bf16*)(ws + 6 * SLOT);
    bf16* qb2  = (bf16*)(ws + 7 * SLOT);
    bf16* kb2  = (bf16*)(ws + 8 * SLOT);
    bf16* vb2  = (bf16*)(ws + 9 * SLOT);  // V^T layout [B,H,Dh,S]
    bf16* attnb = qr;   // reuse after rope_norm

    const int NW = D_ * D_;  // 4194304
    ConvArgs ca;
    ca.s[0] = x;  ca.d[0] = xb;
    ca.s[1] = wq; ca.d[1] = wqb;
    ca.s[2] = wk; ca.d[2] = wkb;
    ca.s[3] = wv; ca.d[3] = wvb;
    ca.s[4] = wo; ca.d[4] = wob;
    conv_all<<<dim3(NW / 2048, 5), dim3(256), 0, stream>>>(ca, NW);

    QKVArgs qa;
    qa.Sc[0] = wq_s; qa.Sc[1] = wk_s; qa.Sc[2] = wv_s;
    qa.qO = qr; qa.kO = kr; qa.vO = vb2;
    gemmQKV<<<dim3(3 * D_ / 192, M_ / 128), dim3(512), 0, stream>>>(xb, wqb, qa);

    rope_norm<<<dim3(M_, 1, 2), dim3(256), 0, stream>>>(qr, kr, qn, kn, cosT, sinT, qb2, kb2);

    flash<<<dim3(S_ / 64, B_ * H_, 1), dim3(256), 0, stream>>>(qb2, kb2, vb2, lengths, attnb);

    gemmO<<<dim3(D_ / 128, M_ / 128), dim3(256), 0, stream>>>(attnb, wob, wo_s, out);
}